// Round 17
// baseline (196.188 us; speedup 1.0000x reference)
//
#include <hip/hip_runtime.h>
#include <math.h>

#define BB 2
#define NN 128
#define DD 128     // DIM
#define DI 256     // H*DH
#define DM 512
#define SS 5
#define SDI 1280   // S*DI
#define HS 40      // H*S
#define M1 3
#define M2 5

typedef __attribute__((ext_vector_type(8))) short bf16x8_t;
typedef __attribute__((ext_vector_type(4))) float f32x4_t;
typedef __attribute__((ext_vector_type(4))) float f32x4v;

#define MFMA __builtin_amdgcn_mfma_f32_16x16x32_bf16

__device__ __forceinline__ float sigm(float x){ return __fdividef(1.0f, 1.0f + __expf(-x)); }
__device__ __forceinline__ unsigned short f2bf(float f){
    union { float f; unsigned u; } v; v.f = f;
    unsigned r = v.u + 0x7FFFu + ((v.u>>16)&1u);   // RNE
    return (unsigned short)(r>>16);
}
__device__ __forceinline__ unsigned pk2(float a, float b){
    return (unsigned)f2bf(a) | ((unsigned)f2bf(b)<<16);
}
__device__ __forceinline__ float bflo(unsigned u){ union{unsigned u; float f;} v; v.u = u<<16; return v.f; }
__device__ __forceinline__ float bfhi(unsigned u){ union{unsigned u; float f;} v; v.u = u & 0xFFFF0000u; return v.f; }

// ---------------------------------------------------------------------------
// prep: weight transposes (bf16), WnT gather, LN, x1/x2 f32 transposes.
// ---------------------------------------------------------------------------
__global__ __launch_bounds__(256) void prep(
    const float* __restrict__ h,
    const float* __restrict__ g_hi, const float* __restrict__ g_hj,
    const float* __restrict__ Wq, const float* __restrict__ Wk,
    const float* __restrict__ Wv1, const float* __restrict__ Wpv1,
    const float* __restrict__ Wg,
    const float* __restrict__ Wek, const float* __restrict__ Wev,
    const float* __restrict__ Wo, const float* __restrict__ Wv2,
    const float* __restrict__ Wpv2,
    const float* __restrict__ x1, const float* __restrict__ x2,
    unsigned short* __restrict__ hi_ws, unsigned short* __restrict__ hj_ws,
    unsigned short* __restrict__ WekT, unsigned short* __restrict__ WevT,
    unsigned short* __restrict__ WoT, unsigned short* __restrict__ W2T,
    unsigned short* __restrict__ WnT,
    float* __restrict__ x1T, float* __restrict__ x2T)
{
    const int bx = blockIdx.x, tid = threadIdx.x;
    __shared__ unsigned short sLT[64*65];
    if (bx < 408){
        const float* src; unsigned short* dst; int W, ldD, R0, C0;
        int t = bx;
        if (t < 160){ src=Wv2;  dst=W2T;            W=SDI; ldD=DM;  R0=(t%20)*64; C0=(t/20)*64; }
        else if (t < 320){ t-=160; src=Wpv2; dst=W2T + SDI*DM; W=SDI; ldD=DM; R0=(t%20)*64; C0=(t/20)*64; }
        else if (t < 360){ t-=320; src=Wek; dst=WekT; W=SDI; ldD=DD; R0=(t%20)*64; C0=(t/20)*64; }
        else if (t < 400){ t-=360; src=Wev; dst=WevT; W=SDI; ldD=DD; R0=(t%20)*64; C0=(t/20)*64; }
        else { t-=400; src=Wo; dst=WoT; W=DD; ldD=DI; R0=(t%2)*64; C0=(t/2)*64; }
        const int tx = tid & 63, ty = tid >> 6;
        #pragma unroll
        for (int k=0;k<16;++k){
            int c = C0 + 4*k + ty;
            sLT[tx*65 + 4*k + ty] = f2bf(src[(size_t)c*W + R0 + tx]);
        }
        __syncthreads();
        #pragma unroll
        for (int k=0;k<16;++k){
            int rr = 4*k + ty;
            dst[(size_t)(R0+rr)*ldD + C0 + tx] = sLT[rr*65 + tx];
        }
    } else if (bx < 664){
        const int node = bx - 408;
        if (tid < 64){
            float h0 = h[node*DD + tid], h1 = h[node*DD + 64 + tid];
            float s1 = h0 + h1, s2 = h0*h0 + h1*h1;
            #pragma unroll
            for (int off=32; off; off>>=1){ s1 += __shfl_xor(s1,off); s2 += __shfl_xor(s2,off); }
            float mu   = s1*(1.0f/DD);
            float var  = s2*(1.0f/DD) - mu*mu;
            float rstd = rsqrtf(var + 1e-5f);
            float c0 = (h0-mu)*rstd, c1 = (h1-mu)*rstd;
            hi_ws[node*DD + tid]      = f2bf(c0*g_hi[tid]);
            hi_ws[node*DD + 64 + tid] = f2bf(c1*g_hi[64+tid]);
            hj_ws[node*DD + tid]      = f2bf(c0*g_hj[tid]);
            hj_ws[node*DD + 64 + tid] = f2bf(c1*g_hj[64+tid]);
        }
        for (int f = node*256 + tid; f < 1584*DD; f += 256*256){
            int row = f >> 7, d = f & 127;
            float v;
            if (row < 256)       v = Wq[d*DI + row];
            else if (row < 304){ int c = row-256; v = (c < HS) ? Wg[d*HS + c] : 0.0f; }
            else if (row < 560)  v = Wk[d*DI + (row-304)];
            else if (row < 1072) v = Wv1[d*DM + (row-560)];
            else                 v = Wpv1[d*DM + (row-1072)];
            WnT[f] = f2bf(v);
        }
    } else {
        const int t = bx - 664;
        const int bb = t >> 7, j = t & 127;
        const int d = tid & 127, half = tid >> 7;
        if (half == 0){
            #pragma unroll
            for (int m=0;m<M1;++m)
                x1T[((size_t)(bb*M1+m)*NN + j)*DD + d] =
                    x1[(((size_t)bb*NN + j)*DD + d)*M1 + m];
        } else {
            #pragma unroll
            for (int m=0;m<M2;++m)
                x2T[((size_t)(bb*M2+m)*NN + j)*DD + d] =
                    x2[(((size_t)bb*NN + j)*DD + d)*M2 + m];
        }
    }
}

// ---------------------------------------------------------------------------
// node_gemm
// ---------------------------------------------------------------------------
__global__ __launch_bounds__(256,4) void node_gemm(
    const unsigned short* __restrict__ WnT,
    const unsigned short* __restrict__ hi_ws, const unsigned short* __restrict__ hj_ws,
    const float* __restrict__ bg, const float* __restrict__ bv1, const float* __restrict__ bpv1,
    float* __restrict__ q_ws, float* __restrict__ k_ws,
    float* __restrict__ g_ws, unsigned short* __restrict__ hid_ws)
{
    const int bx = blockIdx.x;
    const int tile = bx % 99, nq = bx / 99;
    const int tid = threadIdx.x, lane = tid&63, w = tid>>6;
    const int l15 = lane&15, g4 = lane>>4;
    const int ntile = nq*4 + w;
    const unsigned short* A  = WnT + (size_t)(tile*16 + l15)*DD + 8*g4;
    const unsigned short* Bp = ((tile < 19) ? hi_ws : hj_ws) + (size_t)(ntile*16 + l15)*DD + 8*g4;
    f32x4_t c = {0.f,0.f,0.f,0.f};
    #pragma unroll
    for (int ks=0; ks<4; ++ks)
        c = MFMA(*(const bf16x8_t*)(A + 32*ks), *(const bf16x8_t*)(Bp + 32*ks), c, 0,0,0);
    const int node = ntile*16 + l15;
    const int col0 = tile*16 + 4*g4;
    if (tile < 16){
        f32x4_t* dst = (f32x4_t*)(q_ws + (size_t)node*DI + col0);
        *dst = c;
    } else if (tile < 19){
        #pragma unroll
        for (int r=0;r<4;++r){
            int cc = col0 + r - 256;
            if (cc < HS) g_ws[node*HS + cc] = sigm(c[r] + bg[cc]);
        }
    } else if (tile < 35){
        f32x4_t* dst = (f32x4_t*)(k_ws + (size_t)node*DI + (col0-304));
        *dst = c;
    } else if (tile < 67){
        int cc = col0 - 560;
        float s0 = c[0]+bv1[cc], s1 = c[1]+bv1[cc+1], s2 = c[2]+bv1[cc+2], s3 = c[3]+bv1[cc+3];
        s0 *= sigm(s0); s1 *= sigm(s1); s2 *= sigm(s2); s3 *= sigm(s3);
        uint2 pkk; pkk.x = pk2(s0,s1); pkk.y = pk2(s2,s3);
        *(uint2*)(hid_ws + (size_t)node*1024 + cc) = pkk;
    } else {
        int cc = col0 - 1072;
        float s0 = c[0]+bpv1[cc], s1 = c[1]+bpv1[cc+1], s2 = c[2]+bpv1[cc+2], s3 = c[3]+bpv1[cc+3];
        s0 *= sigm(s0); s1 *= sigm(s1); s2 *= sigm(s2); s3 *= sigm(s3);
        uint2 pkk; pkk.x = pk2(s0,s1); pkk.y = pk2(s2,s3);
        *(uint2*)(hid_ws + (size_t)node*1024 + 512 + cc) = pkk;
    }
}

// ---------------------------------------------------------------------------
// v2_gemm
// ---------------------------------------------------------------------------
__global__ __launch_bounds__(256,4) void v2_gemm(
    const unsigned short* __restrict__ W2T,
    const unsigned short* __restrict__ hid_ws,
    const float* __restrict__ bv2, const float* __restrict__ bpv2,
    unsigned short* __restrict__ vpv_ws)
{
    const int bx = blockIdx.x;
    const int otile = bx % 160, nq = bx / 160;
    const int tid = threadIdx.x, lane = tid&63, w = tid>>6;
    const int l15 = lane&15, g4 = lane>>4;
    const int ntile = nq*4 + w;
    const int obase = otile*16;
    const int koff = (obase < SDI) ? 0 : 512;
    const unsigned short* A  = W2T + (size_t)(obase + l15)*DM + 8*g4;
    const unsigned short* Bp = hid_ws + (size_t)(ntile*16 + l15)*1024 + koff + 8*g4;
    f32x4_t c = {0.f,0.f,0.f,0.f};
    #pragma unroll
    for (int ks=0; ks<16; ++ks)
        c = MFMA(*(const bf16x8_t*)(A + 32*ks), *(const bf16x8_t*)(Bp + 32*ks), c, 0,0,0);
    const int node = ntile*16 + l15;
    const int o0 = obase + 4*g4;
    const float* bias = (obase < SDI) ? bv2 : bpv2;
    const int ob = (obase < SDI) ? o0 : (o0 - SDI);
    float v0 = c[0]+bias[ob], v1 = c[1]+bias[ob+1], v2 = c[2]+bias[ob+2], v3 = c[3]+bias[ob+3];
    uint2 pkk; pkk.x = pk2(v0,v1); pkk.y = pk2(v2,v3);
    *(uint2*)(vpv_ws + (size_t)node*2560 + o0) = pkk;
}

// ---------------------------------------------------------------------------
// simh (round-13 version): sim[j,h,s] per (node, j-half). LDS 60416.
// ---------------------------------------------------------------------------
#define SH_T   0
#define SH_QK  16384
#define SH_SIM 49152
#define SH_Q   59392

__global__ __launch_bounds__(512,4) void simh(
    const float* __restrict__ t_ij,
    const unsigned short* __restrict__ WekT,
    const float* __restrict__ q_ws, const float* __restrict__ k_ws,
    float* __restrict__ sim_ws)
{
    __shared__ __align__(16) char sm[60416];
    float* sSIM = (float*)(sm + SH_SIM);
    float* sQf  = (float*)(sm + SH_Q);

    const int bx0 = blockIdx.x;
    const int bx = ((bx0 & 7) << 6) | (bx0 >> 3);
    const int node = bx >> 1, jh = bx & 1;
    const int b = node >> 7;
    const int j0 = jh*64;
    const int tid = threadIdx.x, lane = tid&63, w = tid>>6;
    const int l15 = lane&15, g4 = lane>>4;

    if (tid < DI) sQf[tid] = q_ws[(size_t)node*DI + tid];
    {
        const int j = tid>>3, seg = tid&7;
        const float* src = t_ij + (size_t)(node*NN + j0 + j)*DD + seg*16;
        char* row = sm + SH_T + j*256;
        const int swz = (j&7)<<4;
        #pragma unroll
        for (int u=0;u<4;++u){
            f32x4v tv = __builtin_nontemporal_load((const f32x4v*)(src + 4*u));
            uint2 pkk; pkk.x = pk2(tv[0],tv[1]); pkk.y = pk2(tv[2],tv[3]);
            *(uint2*)(row + ((2*(seg*16+4*u)) ^ swz)) = pkk;
        }
    }
    __syncthreads();
    {
        const int j = tid>>3, seg = tid&7;
        const float* kr = k_ws + (size_t)(b*NN + j0 + j)*DI + seg*32;
        char* row = sm + SH_QK + j*512;
        const int swz = (j&7)<<4;
        #pragma unroll
        for (int u=0;u<8;++u){
            float4 kv = *(const float4*)(kr + 4*u);
            const float* qv = sQf + seg*32 + 4*u;
            uint2 pkk; pkk.x = pk2(kv.x*qv[0], kv.y*qv[1]); pkk.y = pk2(kv.z*qv[2], kv.w*qv[3]);
            *(uint2*)(row + ((2*(seg*32+4*u)) ^ swz)) = pkk;
        }
    }
    bf16x8_t bT[4][4];
    #pragma unroll
    for (int jt=0;jt<4;++jt){
        const int jc = jt*16 + l15;
        const char* row = sm + SH_T + jc*256;
        const int swz = (jc&7)<<4;
        #pragma unroll
        for (int ks=0;ks<4;++ks)
            bT[jt][ks] = *(const bf16x8_t*)(row + ((2*(32*ks+8*g4)) ^ swz));
    }
    __syncthreads();

    for (int p5=0; p5<5; ++p5){
        const int p = w + 8*p5;
        const unsigned short* ap = WekT + (size_t)(2*p)*16*DD + (size_t)l15*DD + 8*g4;
        bf16x8_t a0[4], a1[4];
        #pragma unroll
        for (int ks=0;ks<4;++ks){
            a0[ks] = *(const bf16x8_t*)(ap + 32*ks);
            a1[ks] = *(const bf16x8_t*)(ap + 16*DD + 32*ks);
        }
        const int hs = w*SS + p5;
        const int o0 = 32*p + 4*g4;
        const int qk0 = o0 & 255;
        #pragma unroll
        for (int jt=0;jt<4;++jt){
            f32x4_t c0 = {0.f,0.f,0.f,0.f}, c1 = {0.f,0.f,0.f,0.f};
            #pragma unroll
            for (int ks=0;ks<4;++ks){
                c0 = MFMA(a0[ks], bT[jt][ks], c0, 0,0,0);
                c1 = MFMA(a1[ks], bT[jt][ks], c1, 0,0,0);
            }
            const int jr = jt*16 + l15;
            const char* qrow = sm + SH_QK + jr*512;
            const int swz = (jr&7)<<4;
            uint2 u0 = *(const uint2*)(qrow + ((2*qk0) ^ swz));
            uint2 u1 = *(const uint2*)(qrow + ((2*(qk0+16)) ^ swz));
            float part =
                (c0[0]*sigm(c0[0]))*bflo(u0.x) + (c0[1]*sigm(c0[1]))*bfhi(u0.x)
              + (c0[2]*sigm(c0[2]))*bflo(u0.y) + (c0[3]*sigm(c0[3]))*bfhi(u0.y)
              + (c1[0]*sigm(c1[0]))*bflo(u1.x) + (c1[1]*sigm(c1[1]))*bfhi(u1.x)
              + (c1[2]*sigm(c1[2]))*bflo(u1.y) + (c1[3]*sigm(c1[3]))*bfhi(u1.y);
            part += __shfl_xor(part, 16);
            part += __shfl_xor(part, 32);
            if (g4 == 0) sSIM[jr*HS + hs] = part;
        }
    }
    __syncthreads();
    {
        float* dst = sim_ws + (size_t)node*NN*HS + j0*HS;
        for (int t2=tid; t2<64*HS; t2+=512) dst[t2] = sSIM[t2];
    }
}

// ---------------------------------------------------------------------------
// softmax_k: in-place softmax over j on sim_ws, PRE-SCALED by gate[i,h,s].
// ---------------------------------------------------------------------------
__global__ __launch_bounds__(256) void softmax_k(
    float* __restrict__ sim_ws, const float* __restrict__ g_ws)
{
    const int node = blockIdx.x;
    const int tid = threadIdx.x, lane = tid&63, w = tid>>6;
    float* srow = sim_ws + (size_t)node*NN*HS;
    #pragma unroll
    for (int u=0; u<10; ++u){
        const int hs = w*10 + u;
        const float gt = g_ws[node*HS + hs];
        float v0 = srow[lane*HS + hs];
        float v1 = srow[(lane+64)*HS + hs];
        float m = fmaxf(v0,v1);
        #pragma unroll
        for (int off=32; off; off>>=1) m = fmaxf(m, __shfl_xor(m,off));
        float e0 = __expf(v0-m), e1 = __expf(v1-m);
        float ssum = e0+e1;
        #pragma unroll
        for (int off=32; off; off>>=1) ssum += __shfl_xor(ssum,off);
        float inv = __fdividef(gt, ssum);
        srow[lane*HS + hs]      = e0*inv;
        srow[(lane+64)*HS + hs] = e1*inv;
    }
}

// ---------------------------------------------------------------------------
// shared EV macro (quarter version, 2 j-tiles).
// ---------------------------------------------------------------------------
#define EV_BODY(S, ATTIDX, EPILOG)                                                \
    _Pragma("unroll")                                                             \
    for (int mloc=0; mloc<2; ++mloc){                                             \
        const int mt = w*2 + mloc;                                                \
        const int m0 = mt*16 + 4*g4;                                              \
        uint2 vvr[2], ppr[2];                                                     \
        _Pragma("unroll")                                                         \
        for (int jt=0;jt<2;++jt){                                                 \
            const unsigned short* vb = vpv_ws + (size_t)(b*NN + j0 + jt*16 + l15)*2560 + (S)*DI + m0; \
            vvr[jt] = *(const uint2*)vb;                                          \
            ppr[jt] = *(const uint2*)(vb + SDI);                                  \
        }                                                                         \
        const unsigned short* ap = WevT + (size_t)((S)*DI + mt*16 + l15)*DD + 8*g4; \
        bf16x8_t aa[4];                                                           \
        _Pragma("unroll")                                                         \
        for (int ks=0;ks<4;++ks) aa[ks] = *(const bf16x8_t*)(ap + 32*ks);         \
        const int hh = mt >> 1;                                                   \
        const float gtv = sG[hh*SS + (S)];                                        \
        _Pragma("unroll")                                                         \
        for (int jt=0;jt<2;++jt){                                                 \
            const int jc = jt*16 + l15;                                           \
            bf16x8_t bT[4];                                                       \
            {   const char* row_ = sm + jc*256;                                   \
                const int swz_ = (jc&7)<<4;                                       \
                _Pragma("unroll")                                                 \
                for (int ks=0;ks<4;++ks)                                          \
                    bT[ks] = *(const bf16x8_t*)(row_ + ((2*(32*ks+8*g4)) ^ swz_)); } \
            f32x4_t c = {0.f,0.f,0.f,0.f};                                        \
            _Pragma("unroll")                                                     \
            for (int ks=0;ks<4;++ks) c = MFMA(aa[ks], bT[ks], c, 0,0,0);          \
            const float atv = sATT[ATTIDX];                                       \
            float g_[4];                                                          \
            g_[0] = atv*bflo(vvr[jt].x) + gtv*c[0]*bflo(ppr[jt].x);               \
            g_[1] = atv*bfhi(vvr[jt].x) + gtv*c[1]*bfhi(ppr[jt].x);               \
            g_[2] = atv*bflo(vvr[jt].y) + gtv*c[2]*bflo(ppr[jt].y);               \
            g_[3] = atv*bfhi(vvr[jt].y) + gtv*c[3]*bfhi(ppr[jt].y);               \
            EPILOG                                                                \
        }                                                                         \
    }

#define RED_WRITE(VAL, ROW, T_)                                                   \
    { float v_ = (VAL);                                                           \
      v_ += __shfl_xor(v_,1); v_ += __shfl_xor(v_,2);                             \
      v_ += __shfl_xor(v_,4); v_ += __shfl_xor(v_,8);                             \
      if (l15 == 0)                                                               \
          pdst[(ROW)*256 + (w*2 + ((T_)>>2))*16 + 4*g4 + ((T_)&3)] = f2bf(v_); }

// ---------------------------------------------------------------------------
// out_s012: s=0,1,2 register j-contraction. grid 1024 (j-quarters, 32 j).
// LDS: T @0 8K | ATT @8192 (32x24 f32) | G @11264 | W1 @11424 | W2 @11808.
// p012b out: bf16 [qt*256+node][9][256].
// ---------------------------------------------------------------------------
__global__ __launch_bounds__(512,4) void out_s012(
    const float* __restrict__ t_ij,
    const unsigned short* __restrict__ WevT,
    const unsigned short* __restrict__ vpv_ws,
    const float* __restrict__ attn_ws,   // gate-pre-scaled
    const float* __restrict__ g_ws,
    const float* __restrict__ r1, const float* __restrict__ r2,
    unsigned short* __restrict__ p012b)
{
    __shared__ __align__(16) char sm[12448];
    float* sATT = (float*)(sm + 8192);    // [32 j][24 = h*3 + s]
    float* sG   = (float*)(sm + 11264);
    float* sW1  = (float*)(sm + 11424);
    float* sW2  = (float*)(sm + 11808);

    const int bx0 = blockIdx.x;
    const int bx = ((bx0 & 7) << 7) | (bx0 >> 3);   // XCD remap (1024 blocks)
    const int node = bx >> 2, qt = bx & 3;
    const int b = node >> 7;
    const int j0 = qt*32;
    const int tid = threadIdx.x, lane = tid&63, w = tid>>6;
    const int l15 = lane&15, g4 = lane>>4;

    {   // stage T (32 rows)
        const int j = tid>>4, seg = tid&15;
        const float* src = t_ij + (size_t)(node*NN + j0 + j)*DD + seg*8;
        char* row = sm + j*256;
        const int swz = (j&7)<<4;
        #pragma unroll
        for (int u=0;u<2;++u){
            f32x4v tv = __builtin_nontemporal_load((const f32x4v*)(src + 4*u));
            uint2 pkk; pkk.x = pk2(tv[0],tv[1]); pkk.y = pk2(tv[2],tv[3]);
            *(uint2*)(row + ((2*(seg*8+4*u)) ^ swz)) = pkk;
        }
    }
    {   // attn slice for s=0..2
        const float* asrc = attn_ws + (size_t)node*NN*HS + j0*HS;
        for (int t2=tid; t2<32*24; t2+=512){
            int j = t2/24, rem = t2 - 24*j, hh = rem/3, s = rem - 3*hh;
            sATT[t2] = asrc[j*HS + hh*SS + s];
        }
    }
    if (tid < HS) sG[tid] = g_ws[node*HS + tid];
    if (tid < 32*M1) sW1[tid] = r1[((size_t)node*NN + j0)*M1 + tid];
    if (tid < 32*M2) sW2[tid] = r2[((size_t)node*NN + j0)*M2 + tid];
    __syncthreads();

    unsigned short* pdst = p012b + (size_t)(qt*256 + node)*9*256;

    {
        float a0[8] = {0,0,0,0,0,0,0,0};
        EV_BODY(0, jc*24 + hh*3 + 0, {
            _Pragma("unroll")
            for (int k_=0;k_<4;++k_) a0[mloc*4+k_] += g_[k_];
        })
        #pragma unroll
        for (int t_=0;t_<8;++t_) RED_WRITE(a0[t_], 0, t_)
    }
    {
        float a1[M1][8];
        #pragma unroll
        for (int m_=0;m_<M1;++m_)
            #pragma unroll
            for (int t_=0;t_<8;++t_) a1[m_][t_] = 0.f;
        EV_BODY(1, jc*24 + hh*3 + 1, {
            _Pragma("unroll")
            for (int m_=0;m_<M1;++m_){
                const float wgt = sW1[jc*M1 + m_];
                _Pragma("unroll")
                for (int k_=0;k_<4;++k_) a1[m_][mloc*4+k_] = fmaf(wgt, g_[k_], a1[m_][mloc*4+k_]);
            }
        })
        #pragma unroll
        for (int m_=0;m_<M1;++m_)
            #pragma unroll
            for (int t_=0;t_<8;++t_) RED_WRITE(a1[m_][t_], 1+m_, t_)
    }
    {
        float a2[M2][8];
        #pragma unroll
        for (int m_=0;m_<M2;++m_)
            #pragma unroll
            for (int t_=0;t_<8;++t_) a2[m_][t_] = 0.f;
        EV_BODY(2, jc*24 + hh*3 + 2, {
            _Pragma("unroll")
            for (int m_=0;m_<M2;++m_){
                const float wgt = sW2[jc*M2 + m_];
                _Pragma("unroll")
                for (int k_=0;k_<4;++k_) a2[m_][mloc*4+k_] = fmaf(wgt, g_[k_], a2[m_][mloc*4+k_]);
            }
        })
        #pragma unroll
        for (int m_=0;m_<M2;++m_)
            #pragma unroll
            for (int t_=0;t_<8;++t_) RED_WRITE(a2[m_][t_], 4+m_, t_)
    }
}

// ---------------------------------------------------------------------------
// out_s34: s=3,4 sP -> @Wo -> x reductions. grid 1024 (j-quarters).
// LDS: T @0 8K | P @8192 16K | ATT @24576 (32x16 f32 = 2K) | G @26624.
// p34 out: f32 [bx][8][128].
// ---------------------------------------------------------------------------
#define O34_P  8192

#define P_WRITE34                                                                 \
    { uint2 pkk; pkk.x = pk2(g_[0],g_[1]); pkk.y = pk2(g_[2],g_[3]);              \
      *(uint2*)(sm + O34_P + jc*512 + ((2*m0) ^ ((jc&7)<<4))) = pkk; }

#define WO_X(XT, MM, AX)                                                          \
    _Pragma("unroll")                                                             \
    for (int jt=0; jt<2; ++jt){                                                   \
        float xv[4*(MM)];                                                         \
        _Pragma("unroll")                                                         \
        for (int r_=0;r_<4;++r_){                                                 \
            const int jr = j0 + jt*16 + 4*g4 + r_;                                \
            _Pragma("unroll")                                                     \
            for (int m_=0;m_<(MM);++m_)                                           \
                xv[r_*(MM)+m_] = XT[((size_t)(b*(MM)+m_)*NN + jr)*DD + d];        \
        }                                                                         \
        const int arow = jt*16 + l15;                                             \
        const char* pbp = sm + O34_P + arow*512;                                  \
        const int aswz = (arow&7)<<4;                                             \
        f32x4_t c = {0.f,0.f,0.f,0.f};                                            \
        _Pragma("unroll")                                                         \
        for (int ks=0;ks<8;++ks){                                                 \
            bf16x8_t a = *(const bf16x8_t*)(pbp + ((64*ks + 16*g4) ^ aswz));      \
            c = MFMA(a, bWo[ks], c, 0,0,0);                                       \
        }                                                                         \
        _Pragma("unroll")                                                         \
        for (int r_=0;r_<4;++r_){                                                 \
            _Pragma("unroll")                                                     \
            for (int m_=0;m_<(MM);++m_) AX[m_] = fmaf(xv[r_*(MM)+m_], c[r_], AX[m_]); \
        }                                                                         \
    }

__global__ __launch_bounds__(512,4) void out_s34(
    const float* __restrict__ t_ij,
    const unsigned short* __restrict__ WevT, const unsigned short* __restrict__ WoT,
    const unsigned short* __restrict__ vpv_ws,
    const float* __restrict__ attn_ws,   // gate-pre-scaled
    const float* __restrict__ g_ws,
    const float* __restrict__ x1T, const float* __restrict__ x2T,
    float* __restrict__ p34)
{
    __shared__ __align__(16) char sm[26784];
    float* sATT = (float*)(sm + 24576);   // [32 j][16 = h*2 + (s-3)]
    float* sG   = (float*)(sm + 26624);

    const int bx0 = blockIdx.x;
    const int bx = ((bx0 & 7) << 7) | (bx0 >> 3);   // XCD remap (1024 blocks)
    const int node = bx >> 2, qt = bx & 3;
    const int b = node >> 7;
    const int j0 = qt*32;
    const int tid = threadIdx.x, lane = tid&63, w = tid>>6;
    const int l15 = lane&15, g4 = lane>>4;

    {   // stage T (32 rows)
        const int j = tid>>4, seg = tid&15;
        const float* src = t_ij + (size_t)(node*NN + j0 + j)*DD + seg*8;
        char* row = sm + j*256;
        const int swz = (j&7)<<4;
        #pragma unroll
        for (int u=0;u<2;++u){
            f32x4v tv = __builtin_nontemporal_load((const f32x4v*)(src + 4*u));
            uint2 pkk; pkk.x = pk2(tv[0],tv[1]); pkk.y = pk2(tv[2],tv[3]);
            *(uint2*)(row + ((2*(seg*8+4*u)) ^ swz)) = pkk;
        }
    }
    if (tid < 32*16){   // attn slice for s=3,4
        const float* asrc = attn_ws + (size_t)node*NN*HS + j0*HS;
        int j = tid>>4, rem = tid & 15, hh = rem>>1, s = 3 + (rem&1);
        sATT[tid] = asrc[j*HS + hh*SS + s];
    }
    if (tid < HS) sG[tid] = g_ws[node*HS + tid];
    bf16x8_t bWo[8];
    {
        const unsigned short* wr = WoT + (size_t)(w*16 + l15)*DI + 8*g4;
        #pragma unroll
        for (int ks=0;ks<8;++ks) bWo[ks] = *(const bf16x8_t*)(wr + 32*ks);
    }
    __syncthreads();

    const int d = w*16 + l15;
    float ax1[M1] = {0.f,0.f,0.f};
    float ax2[M2] = {0.f,0.f,0.f,0.f,0.f};

    EV_BODY(3, jc*16 + hh*2 + 0, P_WRITE34)
    __syncthreads();
    WO_X(x1T, M1, ax1)
    __syncthreads();
    EV_BODY(4, jc*16 + hh*2 + 1, P_WRITE34)
    __syncthreads();
    WO_X(x2T, M2, ax2)

    // reduce ax over g4, write p34
    {
        float v0 = ax1[0], v1 = ax1[1], v2 = ax1[2];
        float v3 = ax2[0], v4 = ax2[1], v5 = ax2[2], v6 = ax2[3], v7 = ax2[4];
        v0 += __shfl_xor(v0,16); v0 += __shfl_xor(v0,32);
        v1 += __shfl_xor(v1,16); v1 += __shfl_xor(v1,32);
        v2 += __shfl_xor(v2,16); v2 += __shfl_xor(v2,32);
        v3 += __shfl_xor(v3,16); v3 += __shfl_xor(v3,32);
        v4 += __shfl_xor(v4,16); v4 += __shfl_xor(v4,32);
        v5 += __shfl_xor(v5,16); v5 += __shfl_xor(v5,32);
        v6 += __shfl_xor(v6,16); v6 += __shfl_xor(v6,32);
        v7 += __shfl_xor(v7,16); v7 += __shfl_xor(v7,32);
        if (g4 == 0){
            float* pb = p34 + (size_t)bx*8*DD + d;
            pb[0*DD] = v0; pb[1*DD] = v1; pb[2*DD] = v2;
            pb[3*DD] = v3; pb[4*DD] = v4; pb[5*DD] = v5;
            pb[6*DD] = v6; pb[7*DD] = v7;
        }
    }
}

// ---------------------------------------------------------------------------
// combine: z = sum(4 p012 quarters, bf16); out = z@Wo + p34 sums + residual.
// ---------------------------------------------------------------------------
__global__ __launch_bounds__(128) void combine(
    const float* __restrict__ h, const unsigned short* __restrict__ WoT,
    const unsigned short* __restrict__ p012b, const float* __restrict__ p34,
    float* __restrict__ out_h, float* __restrict__ out_x1, float* __restrict__ out_x2)
{
    __shared__ float sZ[256*12];
    const int node = blockIdx.x, d = threadIdx.x;
    for (int t=d; t<2304; t+=128){
        int m = t >> 8, c = t & 255;
        float s = 0.f;
        #pragma unroll
        for (int q=0;q<4;++q)
            s += bflo((unsigned)p012b[((size_t)(q*256 + node)*9)*256 + t]);
        sZ[c*12 + m] = s;
    }
    __syncthreads();
    float az[9] = {0.f,0.f,0.f,0.f,0.f,0.f,0.f,0.f,0.f};
    const unsigned short* wr = WoT + (size_t)d*DI;
    for (int cb=0; cb<32; ++cb){
        uint4 wv = *(const uint4*)(wr + cb*8);
        float wk[8];
        wk[0]=bflo(wv.x); wk[1]=bfhi(wv.x); wk[2]=bflo(wv.y); wk[3]=bfhi(wv.y);
        wk[4]=bflo(wv.z); wk[5]=bfhi(wv.z); wk[6]=bflo(wv.w); wk[7]=bfhi(wv.w);
        #pragma unroll
        for (int k=0;k<8;++k){
            const float* zb = sZ + (cb*8+k)*12;
            float4 za = *(const float4*)zb;
            float4 zbv = *(const float4*)(zb+4);
            float z8 = zb[8];
            az[0] = fmaf(za.x,  wk[k], az[0]);
            az[1] = fmaf(za.y,  wk[k], az[1]);
            az[2] = fmaf(za.z,  wk[k], az[2]);
            az[3] = fmaf(za.w,  wk[k], az[3]);
            az[4] = fmaf(zbv.x, wk[k], az[4]);
            az[5] = fmaf(zbv.y, wk[k], az[5]);
            az[6] = fmaf(zbv.z, wk[k], az[6]);
            az[7] = fmaf(zbv.w, wk[k], az[7]);
            az[8] = fmaf(z8,    wk[k], az[8]);
        }
    }
    float p34v[8];
    #pragma unroll
    for (int row=0; row<8; ++row){
        float s = 0.f;
        #pragma unroll
        for (int q=0;q<4;++q)
            s += p34[((size_t)(node*4+q)*8 + row)*DD + d];
        p34v[row] = s;
    }
    out_h[(size_t)node*DD + d] = h[(size_t)node*DD + d] + az[0];
    #pragma unroll
    for (int m=0;m<M1;++m)
        out_x1[((size_t)node*DD + d)*M1 + m] = az[1+m] + p34v[m];
    #pragma unroll
    for (int m=0;m<M2;++m)
        out_x2[((size_t)node*DD + d)*M2 + m] = az[4+m] + p34v[3+m];
}

// ---------------------------------------------------------------------------
extern "C" void kernel_launch(void* const* d_in, const int* in_sizes, int n_in,
                              void* d_out, int out_size, void* d_ws, size_t ws_size,
                              hipStream_t stream)
{
    (void)in_sizes; (void)n_in; (void)out_size; (void)ws_size;
    const float* h    = (const float*)d_in[0];
    const float* t_ij = (const float*)d_in[1];
    const float* r1   = (const float*)d_in[2];
    const float* r2   = (const float*)d_in[3];
    const float* x1   = (const float*)d_in[4];
    const float* x2   = (const float*)d_in[5];
    const float* g_hi = (const float*)d_in[6];
    const float* g_hj = (const float*)d_in[7];
    const float* Wq   = (const float*)d_in[8];
    const float* Wk   = (const float*)d_in[9];
    const float* Wv1  = (const float*)d_in[10];
    const float* bv1  = (const float*)d_in[11];
    const float* Wv2  = (const float*)d_in[12];
    const float* bv2  = (const float*)d_in[13];
    const float* Wpv1 = (const float*)d_in[14];
    const float* bpv1 = (const float*)d_in[15];
    const float* Wpv2 = (const float*)d_in[16];
    const float* bpv2 = (const float*)d_in[17];
    const float* Wek  = (const float*)d_in[18];
    const float* Wev  = (const float*)d_in[19];
    const float* Wg   = (const float*)d_in[20];
    const float* bg   = (const float*)d_in[21];
    const float* Wo   = (const float*)d_in[22];

    float* fb     = (float*)d_ws;
    float* q_ws   = fb;                       // 65536
    float* k_ws   = q_ws   + 65536;           // 65536
    float* g_ws   = k_ws   + 65536;           // 10240
    float* sim_ws = g_ws   + 10240;           // 1310720
    float* p34    = sim_ws + 1310720;         // 1048576
    float* x1T    = p34    + 1048576;         // 98304
    float* x2T    = x1T    + 98304;           // 163840
    unsigned short* p012b  = (unsigned short*)(x2T + 163840);  // 2359296
    unsigned short* hi_ws  = p012b  + 2359296;
    unsigned short* hj_ws  = hi_ws  + 32768;
    unsigned short* hid_ws = hj_ws  + 32768;  // 262144
    unsigned short* vpv_ws = hid_ws + 262144; // 655360
    unsigned short* WekT   = vpv_ws + 655360; // 163840
    unsigned short* WevT   = WekT   + 163840; // 163840
    unsigned short* WoT    = WevT   + 163840; // 32768
    unsigned short* W2T    = WoT    + 32768;  // 1310720
    unsigned short* WnT    = W2T    + 1310720;// 202752

    float* out_h  = (float*)d_out;
    float* out_x1 = out_h  + BB*NN*DD;
    float* out_x2 = out_x1 + BB*NN*DD*M1;

    prep<<<920, 256, 0, stream>>>(h, g_hi, g_hj, Wq, Wk, Wv1, Wpv1, Wg,
        Wek, Wev, Wo, Wv2, Wpv2, x1, x2,
        hi_ws, hj_ws, WekT, WevT, WoT, W2T, WnT, x1T, x2T);

    node_gemm<<<396, 256, 0, stream>>>(WnT, hi_ws, hj_ws, bg, bv1, bpv1,
        q_ws, k_ws, g_ws, hid_ws);

    v2_gemm<<<640, 256, 0, stream>>>(W2T, hid_ws, bv2, bpv2, vpv_ws);

    simh<<<512, 512, 0, stream>>>(t_ij, WekT, q_ws, k_ws, sim_ws);

    softmax_k<<<256, 256, 0, stream>>>(sim_ws, g_ws);

    out_s012<<<1024, 512, 0, stream>>>(t_ij, WevT, vpv_ws, sim_ws, g_ws,
        r1, r2, p012b);

    out_s34<<<1024, 512, 0, stream>>>(t_ij, WevT, WoT, vpv_ws, sim_ws, g_ws,
        x1T, x2T, p34);

    combine<<<256, 128, 0, stream>>>(h, WoT, p012b, p34, out_h, out_x1, out_x2);
}

// Round 18
// 176.869 us; speedup vs baseline: 1.1092x; 1.1092x over previous
//
#include <hip/hip_runtime.h>
#include <math.h>

#define BB 2
#define NN 128
#define DD 128     // DIM
#define DI 256     // H*DH
#define DM 512
#define SS 5
#define SDI 1280   // S*DI
#define HS 40      // H*S
#define M1 3
#define M2 5

typedef __attribute__((ext_vector_type(8))) short bf16x8_t;
typedef __attribute__((ext_vector_type(4))) float f32x4_t;
typedef __attribute__((ext_vector_type(4))) float f32x4v;

#define MFMA __builtin_amdgcn_mfma_f32_16x16x32_bf16

__device__ __forceinline__ float sigm(float x){ return __fdividef(1.0f, 1.0f + __expf(-x)); }
__device__ __forceinline__ unsigned short f2bf(float f){
    union { float f; unsigned u; } v; v.f = f;
    unsigned r = v.u + 0x7FFFu + ((v.u>>16)&1u);   // RNE
    return (unsigned short)(r>>16);
}
__device__ __forceinline__ unsigned pk2(float a, float b){
    return (unsigned)f2bf(a) | ((unsigned)f2bf(b)<<16);
}
__device__ __forceinline__ float bflo(unsigned u){ union{unsigned u; float f;} v; v.u = u<<16; return v.f; }
__device__ __forceinline__ float bfhi(unsigned u){ union{unsigned u; float f;} v; v.u = u & 0xFFFF0000u; return v.f; }

// ---------------------------------------------------------------------------
// prep: weight transposes (bf16), WnT gather, LN, x1/x2 f32 transposes.
// ---------------------------------------------------------------------------
__global__ __launch_bounds__(256) void prep(
    const float* __restrict__ h,
    const float* __restrict__ g_hi, const float* __restrict__ g_hj,
    const float* __restrict__ Wq, const float* __restrict__ Wk,
    const float* __restrict__ Wv1, const float* __restrict__ Wpv1,
    const float* __restrict__ Wg,
    const float* __restrict__ Wek, const float* __restrict__ Wev,
    const float* __restrict__ Wo, const float* __restrict__ Wv2,
    const float* __restrict__ Wpv2,
    const float* __restrict__ x1, const float* __restrict__ x2,
    unsigned short* __restrict__ hi_ws, unsigned short* __restrict__ hj_ws,
    unsigned short* __restrict__ WekT, unsigned short* __restrict__ WevT,
    unsigned short* __restrict__ WoT, unsigned short* __restrict__ W2T,
    unsigned short* __restrict__ WnT,
    float* __restrict__ x1T, float* __restrict__ x2T)
{
    const int bx = blockIdx.x, tid = threadIdx.x;
    __shared__ unsigned short sLT[64*65];
    if (bx < 408){
        const float* src; unsigned short* dst; int W, ldD, R0, C0;
        int t = bx;
        if (t < 160){ src=Wv2;  dst=W2T;            W=SDI; ldD=DM;  R0=(t%20)*64; C0=(t/20)*64; }
        else if (t < 320){ t-=160; src=Wpv2; dst=W2T + SDI*DM; W=SDI; ldD=DM; R0=(t%20)*64; C0=(t/20)*64; }
        else if (t < 360){ t-=320; src=Wek; dst=WekT; W=SDI; ldD=DD; R0=(t%20)*64; C0=(t/20)*64; }
        else if (t < 400){ t-=360; src=Wev; dst=WevT; W=SDI; ldD=DD; R0=(t%20)*64; C0=(t/20)*64; }
        else { t-=400; src=Wo; dst=WoT; W=DD; ldD=DI; R0=(t%2)*64; C0=(t/2)*64; }
        const int tx = tid & 63, ty = tid >> 6;
        #pragma unroll
        for (int k=0;k<16;++k){
            int c = C0 + 4*k + ty;
            sLT[tx*65 + 4*k + ty] = f2bf(src[(size_t)c*W + R0 + tx]);
        }
        __syncthreads();
        #pragma unroll
        for (int k=0;k<16;++k){
            int rr = 4*k + ty;
            dst[(size_t)(R0+rr)*ldD + C0 + tx] = sLT[rr*65 + tx];
        }
    } else if (bx < 664){
        const int node = bx - 408;
        if (tid < 64){
            float h0 = h[node*DD + tid], h1 = h[node*DD + 64 + tid];
            float s1 = h0 + h1, s2 = h0*h0 + h1*h1;
            #pragma unroll
            for (int off=32; off; off>>=1){ s1 += __shfl_xor(s1,off); s2 += __shfl_xor(s2,off); }
            float mu   = s1*(1.0f/DD);
            float var  = s2*(1.0f/DD) - mu*mu;
            float rstd = rsqrtf(var + 1e-5f);
            float c0 = (h0-mu)*rstd, c1 = (h1-mu)*rstd;
            hi_ws[node*DD + tid]      = f2bf(c0*g_hi[tid]);
            hi_ws[node*DD + 64 + tid] = f2bf(c1*g_hi[64+tid]);
            hj_ws[node*DD + tid]      = f2bf(c0*g_hj[tid]);
            hj_ws[node*DD + 64 + tid] = f2bf(c1*g_hj[64+tid]);
        }
        for (int f = node*256 + tid; f < 1584*DD; f += 256*256){
            int row = f >> 7, d = f & 127;
            float v;
            if (row < 256)       v = Wq[d*DI + row];
            else if (row < 304){ int c = row-256; v = (c < HS) ? Wg[d*HS + c] : 0.0f; }
            else if (row < 560)  v = Wk[d*DI + (row-304)];
            else if (row < 1072) v = Wv1[d*DM + (row-560)];
            else                 v = Wpv1[d*DM + (row-1072)];
            WnT[f] = f2bf(v);
        }
    } else {
        const int t = bx - 664;
        const int bb = t >> 7, j = t & 127;
        const int d = tid & 127, half = tid >> 7;
        if (half == 0){
            #pragma unroll
            for (int m=0;m<M1;++m)
                x1T[((size_t)(bb*M1+m)*NN + j)*DD + d] =
                    x1[(((size_t)bb*NN + j)*DD + d)*M1 + m];
        } else {
            #pragma unroll
            for (int m=0;m<M2;++m)
                x2T[((size_t)(bb*M2+m)*NN + j)*DD + d] =
                    x2[(((size_t)bb*NN + j)*DD + d)*M2 + m];
        }
    }
}

// ---------------------------------------------------------------------------
// node_gemm
// ---------------------------------------------------------------------------
__global__ __launch_bounds__(256,4) void node_gemm(
    const unsigned short* __restrict__ WnT,
    const unsigned short* __restrict__ hi_ws, const unsigned short* __restrict__ hj_ws,
    const float* __restrict__ bg, const float* __restrict__ bv1, const float* __restrict__ bpv1,
    float* __restrict__ q_ws, float* __restrict__ k_ws,
    float* __restrict__ g_ws, unsigned short* __restrict__ hid_ws)
{
    const int bx = blockIdx.x;
    const int tile = bx % 99, nq = bx / 99;
    const int tid = threadIdx.x, lane = tid&63, w = tid>>6;
    const int l15 = lane&15, g4 = lane>>4;
    const int ntile = nq*4 + w;
    const unsigned short* A  = WnT + (size_t)(tile*16 + l15)*DD + 8*g4;
    const unsigned short* Bp = ((tile < 19) ? hi_ws : hj_ws) + (size_t)(ntile*16 + l15)*DD + 8*g4;
    f32x4_t c = {0.f,0.f,0.f,0.f};
    #pragma unroll
    for (int ks=0; ks<4; ++ks)
        c = MFMA(*(const bf16x8_t*)(A + 32*ks), *(const bf16x8_t*)(Bp + 32*ks), c, 0,0,0);
    const int node = ntile*16 + l15;
    const int col0 = tile*16 + 4*g4;
    if (tile < 16){
        f32x4_t* dst = (f32x4_t*)(q_ws + (size_t)node*DI + col0);
        *dst = c;
    } else if (tile < 19){
        #pragma unroll
        for (int r=0;r<4;++r){
            int cc = col0 + r - 256;
            if (cc < HS) g_ws[node*HS + cc] = sigm(c[r] + bg[cc]);
        }
    } else if (tile < 35){
        f32x4_t* dst = (f32x4_t*)(k_ws + (size_t)node*DI + (col0-304));
        *dst = c;
    } else if (tile < 67){
        int cc = col0 - 560;
        float s0 = c[0]+bv1[cc], s1 = c[1]+bv1[cc+1], s2 = c[2]+bv1[cc+2], s3 = c[3]+bv1[cc+3];
        s0 *= sigm(s0); s1 *= sigm(s1); s2 *= sigm(s2); s3 *= sigm(s3);
        uint2 pkk; pkk.x = pk2(s0,s1); pkk.y = pk2(s2,s3);
        *(uint2*)(hid_ws + (size_t)node*1024 + cc) = pkk;
    } else {
        int cc = col0 - 1072;
        float s0 = c[0]+bpv1[cc], s1 = c[1]+bpv1[cc+1], s2 = c[2]+bpv1[cc+2], s3 = c[3]+bpv1[cc+3];
        s0 *= sigm(s0); s1 *= sigm(s1); s2 *= sigm(s2); s3 *= sigm(s3);
        uint2 pkk; pkk.x = pk2(s0,s1); pkk.y = pk2(s2,s3);
        *(uint2*)(hid_ws + (size_t)node*1024 + 512 + cc) = pkk;
    }
}

// ---------------------------------------------------------------------------
// v2_gemm
// ---------------------------------------------------------------------------
__global__ __launch_bounds__(256,4) void v2_gemm(
    const unsigned short* __restrict__ W2T,
    const unsigned short* __restrict__ hid_ws,
    const float* __restrict__ bv2, const float* __restrict__ bpv2,
    unsigned short* __restrict__ vpv_ws)
{
    const int bx = blockIdx.x;
    const int otile = bx % 160, nq = bx / 160;
    const int tid = threadIdx.x, lane = tid&63, w = tid>>6;
    const int l15 = lane&15, g4 = lane>>4;
    const int ntile = nq*4 + w;
    const int obase = otile*16;
    const int koff = (obase < SDI) ? 0 : 512;
    const unsigned short* A  = W2T + (size_t)(obase + l15)*DM + 8*g4;
    const unsigned short* Bp = hid_ws + (size_t)(ntile*16 + l15)*1024 + koff + 8*g4;
    f32x4_t c = {0.f,0.f,0.f,0.f};
    #pragma unroll
    for (int ks=0; ks<16; ++ks)
        c = MFMA(*(const bf16x8_t*)(A + 32*ks), *(const bf16x8_t*)(Bp + 32*ks), c, 0,0,0);
    const int node = ntile*16 + l15;
    const int o0 = obase + 4*g4;
    const float* bias = (obase < SDI) ? bv2 : bpv2;
    const int ob = (obase < SDI) ? o0 : (o0 - SDI);
    float v0 = c[0]+bias[ob], v1 = c[1]+bias[ob+1], v2 = c[2]+bias[ob+2], v3 = c[3]+bias[ob+3];
    uint2 pkk; pkk.x = pk2(v0,v1); pkk.y = pk2(v2,v3);
    *(uint2*)(vpv_ws + (size_t)node*2560 + o0) = pkk;
}

// ---------------------------------------------------------------------------
// simh: direct-global-write variant. LDS 50176 -> 3 blocks/CU.
// ---------------------------------------------------------------------------
#define SH_T   0
#define SH_QK  16384
#define SH_Q   49152

__global__ __launch_bounds__(512,4) void simh(
    const float* __restrict__ t_ij,
    const unsigned short* __restrict__ WekT,
    const float* __restrict__ q_ws, const float* __restrict__ k_ws,
    float* __restrict__ sim_ws)
{
    __shared__ __align__(16) char sm[50176];
    float* sQf  = (float*)(sm + SH_Q);

    const int bx0 = blockIdx.x;
    const int bx = ((bx0 & 7) << 6) | (bx0 >> 3);   // XCD-contiguous remap
    const int node = bx >> 1, jh = bx & 1;
    const int b = node >> 7;
    const int j0 = jh*64;
    const int tid = threadIdx.x, lane = tid&63, w = tid>>6;
    const int l15 = lane&15, g4 = lane>>4;

    if (tid < DI) sQf[tid] = q_ws[(size_t)node*DI + tid];
    {   // stage T (64 rows) -> swizzled bf16
        const int j = tid>>3, seg = tid&7;
        const float* src = t_ij + (size_t)(node*NN + j0 + j)*DD + seg*16;
        char* row = sm + SH_T + j*256;
        const int swz = (j&7)<<4;
        #pragma unroll
        for (int u=0;u<4;++u){
            f32x4v tv = __builtin_nontemporal_load((const f32x4v*)(src + 4*u));
            uint2 pkk; pkk.x = pk2(tv[0],tv[1]); pkk.y = pk2(tv[2],tv[3]);
            *(uint2*)(row + ((2*(seg*16+4*u)) ^ swz)) = pkk;
        }
    }
    __syncthreads();
    {   // QK build -> swizzled bf16
        const int j = tid>>3, seg = tid&7;
        const float* kr = k_ws + (size_t)(b*NN + j0 + j)*DI + seg*32;
        char* row = sm + SH_QK + j*512;
        const int swz = (j&7)<<4;
        #pragma unroll
        for (int u=0;u<8;++u){
            float4 kv = *(const float4*)(kr + 4*u);
            const float* qv = sQf + seg*32 + 4*u;
            uint2 pkk; pkk.x = pk2(kv.x*qv[0], kv.y*qv[1]); pkk.y = pk2(kv.z*qv[2], kv.w*qv[3]);
            *(uint2*)(row + ((2*(seg*32+4*u)) ^ swz)) = pkk;
        }
    }
    __syncthreads();

    float* srow_out = sim_ws + (size_t)node*NN*HS + j0*HS;
    for (int p5=0; p5<5; ++p5){
        const int p = w + 8*p5;
        const unsigned short* ap = WekT + (size_t)(2*p)*16*DD + (size_t)l15*DD + 8*g4;
        bf16x8_t a0[4], a1[4];
        #pragma unroll
        for (int ks=0;ks<4;++ks){
            a0[ks] = *(const bf16x8_t*)(ap + 32*ks);
            a1[ks] = *(const bf16x8_t*)(ap + 16*DD + 32*ks);
        }
        const int hs = w*SS + p5;
        const int o0 = 32*p + 4*g4;
        const int qk0 = o0 & 255;
        #pragma unroll
        for (int jt=0;jt<4;++jt){
            const int jr = jt*16 + l15;
            bf16x8_t bT[4];
            {
                const char* row = sm + SH_T + jr*256;
                const int swz = (jr&7)<<4;
                #pragma unroll
                for (int ks=0;ks<4;++ks)
                    bT[ks] = *(const bf16x8_t*)(row + ((2*(32*ks+8*g4)) ^ swz));
            }
            f32x4_t c0 = {0.f,0.f,0.f,0.f}, c1 = {0.f,0.f,0.f,0.f};
            #pragma unroll
            for (int ks=0;ks<4;++ks){
                c0 = MFMA(a0[ks], bT[ks], c0, 0,0,0);
                c1 = MFMA(a1[ks], bT[ks], c1, 0,0,0);
            }
            const char* qrow = sm + SH_QK + jr*512;
            const int swz = (jr&7)<<4;
            uint2 u0 = *(const uint2*)(qrow + ((2*qk0) ^ swz));
            uint2 u1 = *(const uint2*)(qrow + ((2*(qk0+16)) ^ swz));
            float part =
                (c0[0]*sigm(c0[0]))*bflo(u0.x) + (c0[1]*sigm(c0[1]))*bfhi(u0.x)
              + (c0[2]*sigm(c0[2]))*bflo(u0.y) + (c0[3]*sigm(c0[3]))*bfhi(u0.y)
              + (c1[0]*sigm(c1[0]))*bflo(u1.x) + (c1[1]*sigm(c1[1]))*bfhi(u1.x)
              + (c1[2]*sigm(c1[2]))*bflo(u1.y) + (c1[3]*sigm(c1[3]))*bfhi(u1.y);
            part += __shfl_xor(part, 16);
            part += __shfl_xor(part, 32);
            if (g4 == 0) srow_out[jr*HS + hs] = part;
        }
    }
}

// ---------------------------------------------------------------------------
// softmax_k: in-place softmax over j on sim_ws, PRE-SCALED by gate[i,h,s].
// ---------------------------------------------------------------------------
__global__ __launch_bounds__(256) void softmax_k(
    float* __restrict__ sim_ws, const float* __restrict__ g_ws)
{
    const int node = blockIdx.x;
    const int tid = threadIdx.x, lane = tid&63, w = tid>>6;
    float* srow = sim_ws + (size_t)node*NN*HS;
    #pragma unroll
    for (int u=0; u<10; ++u){
        const int hs = w*10 + u;
        const float gt = g_ws[node*HS + hs];
        float v0 = srow[lane*HS + hs];
        float v1 = srow[(lane+64)*HS + hs];
        float m = fmaxf(v0,v1);
        #pragma unroll
        for (int off=32; off; off>>=1) m = fmaxf(m, __shfl_xor(m,off));
        float e0 = __expf(v0-m), e1 = __expf(v1-m);
        float ssum = e0+e1;
        #pragma unroll
        for (int off=32; off; off>>=1) ssum += __shfl_xor(ssum,off);
        float inv = __fdividef(gt, ssum);
        srow[lane*HS + hs]      = e0*inv;
        srow[(lane+64)*HS + hs] = e1*inv;
    }
}

// ---------------------------------------------------------------------------
// outh (round-13 exact): per (node, j-half).
//   s=0,1,2: EV GEMM -> f32 gsea -> register j-contraction -> p012
//   s=3,4  : EV GEMM -> sP -> @Wo -> x-weighted reductions -> p34
// ---------------------------------------------------------------------------
#define OH_T   0
#define OH_P   16384
#define OH_AT  49152
#define OH_G   59392
#define OH_W1  59552
#define OH_W2  60320

#define EV_BODY(S, EPILOG)                                                        \
    _Pragma("unroll")                                                             \
    for (int mloc=0; mloc<2; ++mloc){                                             \
        const int mt = w*2 + mloc;                                                \
        const int m0 = mt*16 + 4*g4;                                              \
        uint2 vvr[4], ppr[4];                                                     \
        _Pragma("unroll")                                                         \
        for (int jt=0;jt<4;++jt){                                                 \
            const unsigned short* vb = vpv_ws + (size_t)(b*NN + j0 + jt*16 + l15)*2560 + (S)*DI + m0; \
            vvr[jt] = *(const uint2*)vb;                                          \
            ppr[jt] = *(const uint2*)(vb + SDI);                                  \
        }                                                                         \
        const unsigned short* ap = WevT + (size_t)((S)*DI + mt*16 + l15)*DD + 8*g4; \
        bf16x8_t aa[4];                                                           \
        _Pragma("unroll")                                                         \
        for (int ks=0;ks<4;++ks) aa[ks] = *(const bf16x8_t*)(ap + 32*ks);         \
        const int hh = mt >> 1;                                                   \
        const float gtv = sG[hh*SS + (S)];                                        \
        _Pragma("unroll")                                                         \
        for (int jt=0;jt<4;++jt){                                                 \
            const int jc = jt*16 + l15;                                           \
            bf16x8_t bT[4];                                                       \
            {   const char* row_ = sm + OH_T + jc*256;                            \
                const int swz_ = (jc&7)<<4;                                       \
                _Pragma("unroll")                                                 \
                for (int ks=0;ks<4;++ks)                                          \
                    bT[ks] = *(const bf16x8_t*)(row_ + ((2*(32*ks+8*g4)) ^ swz_)); } \
            f32x4_t c = {0.f,0.f,0.f,0.f};                                        \
            _Pragma("unroll")                                                     \
            for (int ks=0;ks<4;++ks) c = MFMA(aa[ks], bT[ks], c, 0,0,0);          \
            const float atv = sATT[jc*HS + hh*SS + (S)];                          \
            float g_[4];                                                          \
            g_[0] = atv*bflo(vvr[jt].x) + gtv*c[0]*bflo(ppr[jt].x);               \
            g_[1] = atv*bfhi(vvr[jt].x) + gtv*c[1]*bfhi(ppr[jt].x);               \
            g_[2] = atv*bflo(vvr[jt].y) + gtv*c[2]*bflo(ppr[jt].y);               \
            g_[3] = atv*bfhi(vvr[jt].y) + gtv*c[3]*bfhi(ppr[jt].y);               \
            EPILOG                                                                \
        }                                                                         \
    }

#define WO_X(XT, MM, AX)                                                          \
    _Pragma("unroll")                                                             \
    for (int jt=0; jt<4; ++jt){                                                   \
        float xv[4*(MM)];                                                         \
        _Pragma("unroll")                                                         \
        for (int r_=0;r_<4;++r_){                                                 \
            const int jr = j0 + jt*16 + 4*g4 + r_;                                \
            _Pragma("unroll")                                                     \
            for (int m_=0;m_<(MM);++m_)                                           \
                xv[r_*(MM)+m_] = XT[((size_t)(b*(MM)+m_)*NN + jr)*DD + d];        \
        }                                                                         \
        const int arow = jt*16 + l15;                                             \
        const char* pbp = sm + OH_P + arow*512;                                   \
        const int aswz = (arow&7)<<4;                                             \
        f32x4_t c = {0.f,0.f,0.f,0.f};                                            \
        _Pragma("unroll")                                                         \
        for (int ks=0;ks<8;++ks){                                                 \
            bf16x8_t a = *(const bf16x8_t*)(pbp + ((64*ks + 16*g4) ^ aswz));      \
            c = MFMA(a, bWo[ks], c, 0,0,0);                                       \
        }                                                                         \
        _Pragma("unroll")                                                         \
        for (int r_=0;r_<4;++r_){                                                 \
            _Pragma("unroll")                                                     \
            for (int m_=0;m_<(MM);++m_) AX[m_] = fmaf(xv[r_*(MM)+m_], c[r_], AX[m_]); \
        }                                                                         \
    }

#define RED_WRITE(VAL, ROW, T_)                                                   \
    { float v_ = (VAL);                                                           \
      v_ += __shfl_xor(v_,1); v_ += __shfl_xor(v_,2);                             \
      v_ += __shfl_xor(v_,4); v_ += __shfl_xor(v_,8);                             \
      if (l15 == 0)                                                               \
          pdst[(ROW)*256 + (w*2 + ((T_)>>2))*16 + 4*g4 + ((T_)&3)] = v_; }

__global__ __launch_bounds__(512,4) void outh(
    const float* __restrict__ t_ij,
    const unsigned short* __restrict__ WevT, const unsigned short* __restrict__ WoT,
    const unsigned short* __restrict__ vpv_ws,
    const float* __restrict__ attn_ws,   // gate-pre-scaled
    const float* __restrict__ g_ws,
    const float* __restrict__ r1, const float* __restrict__ r2,
    const float* __restrict__ x1T, const float* __restrict__ x2T,
    float* __restrict__ p012, float* __restrict__ p34)
{
    __shared__ __align__(16) char sm[61600];
    float* sATT = (float*)(sm + OH_AT);
    float* sG   = (float*)(sm + OH_G);
    float* sW1  = (float*)(sm + OH_W1);
    float* sW2  = (float*)(sm + OH_W2);

    const int bx0 = blockIdx.x;
    const int bx = ((bx0 & 7) << 6) | (bx0 >> 3);   // XCD-contiguous remap
    const int node = bx >> 1, jh = bx & 1;
    const int b = node >> 7;
    const int j0 = jh*64;
    const int tid = threadIdx.x, lane = tid&63, w = tid>>6;
    const int l15 = lane&15, g4 = lane>>4;

    {   // stage T (64 rows) -> swizzled bf16
        const int j = tid>>3, seg = tid&7;
        const float* src = t_ij + (size_t)(node*NN + j0 + j)*DD + seg*16;
        char* row = sm + OH_T + j*256;
        const int swz = (j&7)<<4;
        #pragma unroll
        for (int u=0;u<4;++u){
            f32x4v tv = __builtin_nontemporal_load((const f32x4v*)(src + 4*u));
            uint2 pkk; pkk.x = pk2(tv[0],tv[1]); pkk.y = pk2(tv[2],tv[3]);
            *(uint2*)(row + ((2*(seg*16+4*u)) ^ swz)) = pkk;
        }
    }
    {
        const float* asrc = attn_ws + (size_t)node*NN*HS + j0*HS;
        for (int t2=tid; t2<64*HS; t2+=512) sATT[t2] = asrc[t2];
    }
    if (tid < HS) sG[tid] = g_ws[node*HS + tid];
    if (tid < 64*M1) sW1[tid] = r1[((size_t)node*NN + j0)*M1 + tid];
    if (tid < 64*M2) sW2[tid] = r2[((size_t)node*NN + j0)*M2 + tid];
    __syncthreads();

    float* pdst = p012 + (size_t)(jh*256 + node)*9*256;

    // ---- s=0 ----
    {
        float a0[8] = {0,0,0,0,0,0,0,0};
        EV_BODY(0, {
            _Pragma("unroll")
            for (int k_=0;k_<4;++k_) a0[mloc*4+k_] += g_[k_];
        })
        #pragma unroll
        for (int t_=0;t_<8;++t_) RED_WRITE(a0[t_], 0, t_)
    }
    // ---- s=1 ----
    {
        float a1[M1][8];
        #pragma unroll
        for (int m_=0;m_<M1;++m_)
            #pragma unroll
            for (int t_=0;t_<8;++t_) a1[m_][t_] = 0.f;
        EV_BODY(1, {
            _Pragma("unroll")
            for (int m_=0;m_<M1;++m_){
                const float wgt = sW1[jc*M1 + m_];
                _Pragma("unroll")
                for (int k_=0;k_<4;++k_) a1[m_][mloc*4+k_] = fmaf(wgt, g_[k_], a1[m_][mloc*4+k_]);
            }
        })
        #pragma unroll
        for (int m_=0;m_<M1;++m_)
            #pragma unroll
            for (int t_=0;t_<8;++t_) RED_WRITE(a1[m_][t_], 1+m_, t_)
    }
    // ---- s=2 ----
    {
        float a2[M2][8];
        #pragma unroll
        for (int m_=0;m_<M2;++m_)
            #pragma unroll
            for (int t_=0;t_<8;++t_) a2[m_][t_] = 0.f;
        EV_BODY(2, {
            _Pragma("unroll")
            for (int m_=0;m_<M2;++m_){
                const float wgt = sW2[jc*M2 + m_];
                _Pragma("unroll")
                for (int k_=0;k_<4;++k_) a2[m_][mloc*4+k_] = fmaf(wgt, g_[k_], a2[m_][mloc*4+k_]);
            }
        })
        #pragma unroll
        for (int m_=0;m_<M2;++m_)
            #pragma unroll
            for (int t_=0;t_<8;++t_) RED_WRITE(a2[m_][t_], 4+m_, t_)
    }

    // ---- s=3,4 ----
    const int d = w*16 + l15;
    bf16x8_t bWo[8];
    {
        const unsigned short* wr = WoT + (size_t)d*DI + 8*g4;
        #pragma unroll
        for (int ks=0;ks<8;++ks) bWo[ks] = *(const bf16x8_t*)(wr + 32*ks);
    }
    float ax1[M1] = {0.f,0.f,0.f};
    float ax2[M2] = {0.f,0.f,0.f,0.f,0.f};

    EV_BODY(3, {
        uint2 pkk; pkk.x = pk2(g_[0],g_[1]); pkk.y = pk2(g_[2],g_[3]);
        *(uint2*)(sm + OH_P + jc*512 + ((2*m0) ^ ((jc&7)<<4))) = pkk;
    })
    __syncthreads();
    WO_X(x1T, M1, ax1)
    __syncthreads();
    EV_BODY(4, {
        uint2 pkk; pkk.x = pk2(g_[0],g_[1]); pkk.y = pk2(g_[2],g_[3]);
        *(uint2*)(sm + OH_P + jc*512 + ((2*m0) ^ ((jc&7)<<4))) = pkk;
    })
    __syncthreads();
    WO_X(x2T, M2, ax2)

    // reduce ax over g4, write p34
    {
        float v0 = ax1[0], v1 = ax1[1], v2 = ax1[2];
        float v3 = ax2[0], v4 = ax2[1], v5 = ax2[2], v6 = ax2[3], v7 = ax2[4];
        v0 += __shfl_xor(v0,16); v0 += __shfl_xor(v0,32);
        v1 += __shfl_xor(v1,16); v1 += __shfl_xor(v1,32);
        v2 += __shfl_xor(v2,16); v2 += __shfl_xor(v2,32);
        v3 += __shfl_xor(v3,16); v3 += __shfl_xor(v3,32);
        v4 += __shfl_xor(v4,16); v4 += __shfl_xor(v4,32);
        v5 += __shfl_xor(v5,16); v5 += __shfl_xor(v5,32);
        v6 += __shfl_xor(v6,16); v6 += __shfl_xor(v6,32);
        v7 += __shfl_xor(v7,16); v7 += __shfl_xor(v7,32);
        if (g4 == 0){
            float* pb = p34 + (size_t)bx*8*DD + d;
            pb[0*DD] = v0; pb[1*DD] = v1; pb[2*DD] = v2;
            pb[3*DD] = v3; pb[4*DD] = v4; pb[5*DD] = v5;
            pb[6*DD] = v6; pb[7*DD] = v7;
        }
    }
}

// ---------------------------------------------------------------------------
// combine: z = sum(p012 halves); out = z @ Wo + p34 sums + residual.
// ---------------------------------------------------------------------------
__global__ __launch_bounds__(128) void combine(
    const float* __restrict__ h, const unsigned short* __restrict__ WoT,
    const float* __restrict__ p012, const float* __restrict__ p34,
    float* __restrict__ out_h, float* __restrict__ out_x1, float* __restrict__ out_x2)
{
    __shared__ float sZ[256*12];
    const int node = blockIdx.x, d = threadIdx.x;
    const float* pa = p012 + ((size_t)node*9)*256;
    const float* pb = p012 + ((size_t)(256 + node)*9)*256;
    for (int t=d; t<2304; t+=128){
        int m = t >> 8, c = t & 255;
        sZ[c*12 + m] = pa[t] + pb[t];
    }
    __syncthreads();
    float az[9] = {0.f,0.f,0.f,0.f,0.f,0.f,0.f,0.f,0.f};
    const unsigned short* wr = WoT + (size_t)d*DI;
    for (int cb=0; cb<32; ++cb){
        uint4 wv = *(const uint4*)(wr + cb*8);
        float wk[8];
        wk[0]=bflo(wv.x); wk[1]=bfhi(wv.x); wk[2]=bflo(wv.y); wk[3]=bfhi(wv.y);
        wk[4]=bflo(wv.z); wk[5]=bfhi(wv.z); wk[6]=bflo(wv.w); wk[7]=bfhi(wv.w);
        #pragma unroll
        for (int k=0;k<8;++k){
            const float* zb = sZ + (cb*8+k)*12;
            float4 za = *(const float4*)zb;
            float4 zbv = *(const float4*)(zb+4);
            float z8 = zb[8];
            az[0] = fmaf(za.x,  wk[k], az[0]);
            az[1] = fmaf(za.y,  wk[k], az[1]);
            az[2] = fmaf(za.z,  wk[k], az[2]);
            az[3] = fmaf(za.w,  wk[k], az[3]);
            az[4] = fmaf(zbv.x, wk[k], az[4]);
            az[5] = fmaf(zbv.y, wk[k], az[5]);
            az[6] = fmaf(zbv.z, wk[k], az[6]);
            az[7] = fmaf(zbv.w, wk[k], az[7]);
            az[8] = fmaf(z8,    wk[k], az[8]);
        }
    }
    float p34v[8];
    #pragma unroll
    for (int row=0; row<8; ++row){
        p34v[row] = p34[((size_t)(node*2+0)*8 + row)*DD + d]
                  + p34[((size_t)(node*2+1)*8 + row)*DD + d];
    }
    out_h[(size_t)node*DD + d] = h[(size_t)node*DD + d] + az[0];
    #pragma unroll
    for (int m=0;m<M1;++m)
        out_x1[((size_t)node*DD + d)*M1 + m] = az[1+m] + p34v[m];
    #pragma unroll
    for (int m=0;m<M2;++m)
        out_x2[((size_t)node*DD + d)*M2 + m] = az[4+m] + p34v[3+m];
}

// ---------------------------------------------------------------------------
extern "C" void kernel_launch(void* const* d_in, const int* in_sizes, int n_in,
                              void* d_out, int out_size, void* d_ws, size_t ws_size,
                              hipStream_t stream)
{
    (void)in_sizes; (void)n_in; (void)out_size; (void)ws_size;
    const float* h    = (const float*)d_in[0];
    const float* t_ij = (const float*)d_in[1];
    const float* r1   = (const float*)d_in[2];
    const float* r2   = (const float*)d_in[3];
    const float* x1   = (const float*)d_in[4];
    const float* x2   = (const float*)d_in[5];
    const float* g_hi = (const float*)d_in[6];
    const float* g_hj = (const float*)d_in[7];
    const float* Wq   = (const float*)d_in[8];
    const float* Wk   = (const float*)d_in[9];
    const float* Wv1  = (const float*)d_in[10];
    const float* bv1  = (const float*)d_in[11];
    const float* Wv2  = (const float*)d_in[12];
    const float* bv2  = (const float*)d_in[13];
    const float* Wpv1 = (const float*)d_in[14];
    const float* bpv1 = (const float*)d_in[15];
    const float* Wpv2 = (const float*)d_in[16];
    const float* bpv2 = (const float*)d_in[17];
    const float* Wek  = (const float*)d_in[18];
    const float* Wev  = (const float*)d_in[19];
    const float* Wg   = (const float*)d_in[20];
    const float* bg   = (const float*)d_in[21];
    const float* Wo   = (const float*)d_in[22];

    float* fb     = (float*)d_ws;
    float* q_ws   = fb;                       // 65536
    float* k_ws   = q_ws   + 65536;           // 65536
    float* g_ws   = k_ws   + 65536;           // 10240
    float* sim_ws = g_ws   + 10240;           // 1310720
    float* p012   = sim_ws + 1310720;         // 1179648
    float* p34    = p012   + 1179648;         // 524288
    float* x1T    = p34    + 524288;          // 98304
    float* x2T    = x1T    + 98304;           // 163840
    unsigned short* hi_ws  = (unsigned short*)(x2T + 163840);
    unsigned short* hj_ws  = hi_ws  + 32768;
    unsigned short* hid_ws = hj_ws  + 32768;  // 262144
    unsigned short* vpv_ws = hid_ws + 262144; // 655360
    unsigned short* WekT   = vpv_ws + 655360; // 163840
    unsigned short* WevT   = WekT   + 163840; // 163840
    unsigned short* WoT    = WevT   + 163840; // 32768
    unsigned short* W2T    = WoT    + 32768;  // 1310720
    unsigned short* WnT    = W2T    + 1310720;// 202752

    float* out_h  = (float*)d_out;
    float* out_x1 = out_h  + BB*NN*DD;
    float* out_x2 = out_x1 + BB*NN*DD*M1;

    prep<<<920, 256, 0, stream>>>(h, g_hi, g_hj, Wq, Wk, Wv1, Wpv1, Wg,
        Wek, Wev, Wo, Wv2, Wpv2, x1, x2,
        hi_ws, hj_ws, WekT, WevT, WoT, W2T, WnT, x1T, x2T);

    node_gemm<<<396, 256, 0, stream>>>(WnT, hi_ws, hj_ws, bg, bv1, bpv1,
        q_ws, k_ws, g_ws, hid_ws);

    v2_gemm<<<640, 256, 0, stream>>>(W2T, hid_ws, bv2, bpv2, vpv_ws);

    simh<<<512, 512, 0, stream>>>(t_ij, WekT, q_ws, k_ws, sim_ws);

    softmax_k<<<256, 256, 0, stream>>>(sim_ws, g_ws);

    outh<<<512, 512, 0, stream>>>(t_ij, WevT, WoT, vpv_ws, sim_ws, g_ws,
        r1, r2, x1T, x2T, p012, p34);

    combine<<<256, 128, 0, stream>>>(h, WoT, p012, p34, out_h, out_x1, out_x2);
}

// Round 19
// 168.200 us; speedup vs baseline: 1.1664x; 1.0515x over previous
//
#include <hip/hip_runtime.h>
#include <math.h>

#define BB 2
#define NN 128
#define DD 128     // DIM
#define DI 256     // H*DH
#define DM 512
#define SS 5
#define SDI 1280   // S*DI
#define HS 40      // H*S
#define M1 3
#define M2 5

typedef __attribute__((ext_vector_type(8))) short bf16x8_t;
typedef __attribute__((ext_vector_type(4))) float f32x4_t;
typedef __attribute__((ext_vector_type(4))) float f32x4v;

#define MFMA __builtin_amdgcn_mfma_f32_16x16x32_bf16

__device__ __forceinline__ float sigm(float x){ return __fdividef(1.0f, 1.0f + __expf(-x)); }
__device__ __forceinline__ unsigned short f2bf(float f){
    union { float f; unsigned u; } v; v.f = f;
    unsigned r = v.u + 0x7FFFu + ((v.u>>16)&1u);   // RNE
    return (unsigned short)(r>>16);
}
__device__ __forceinline__ unsigned pk2(float a, float b){
    return (unsigned)f2bf(a) | ((unsigned)f2bf(b)<<16);
}
__device__ __forceinline__ float bflo(unsigned u){ union{unsigned u; float f;} v; v.u = u<<16; return v.f; }
__device__ __forceinline__ float bfhi(unsigned u){ union{unsigned u; float f;} v; v.u = u & 0xFFFF0000u; return v.f; }

// ---------------------------------------------------------------------------
// prep: weight transposes (bf16), WnT gather, LN, x1/x2 f32 transposes.
// ---------------------------------------------------------------------------
__global__ __launch_bounds__(256) void prep(
    const float* __restrict__ h,
    const float* __restrict__ g_hi, const float* __restrict__ g_hj,
    const float* __restrict__ Wq, const float* __restrict__ Wk,
    const float* __restrict__ Wv1, const float* __restrict__ Wpv1,
    const float* __restrict__ Wg,
    const float* __restrict__ Wek, const float* __restrict__ Wev,
    const float* __restrict__ Wo, const float* __restrict__ Wv2,
    const float* __restrict__ Wpv2,
    const float* __restrict__ x1, const float* __restrict__ x2,
    unsigned short* __restrict__ hi_ws, unsigned short* __restrict__ hj_ws,
    unsigned short* __restrict__ WekT, unsigned short* __restrict__ WevT,
    unsigned short* __restrict__ WoT, unsigned short* __restrict__ W2T,
    unsigned short* __restrict__ WnT,
    float* __restrict__ x1T, float* __restrict__ x2T)
{
    const int bx = blockIdx.x, tid = threadIdx.x;
    __shared__ unsigned short sLT[64*65];
    if (bx < 408){
        const float* src; unsigned short* dst; int W, ldD, R0, C0;
        int t = bx;
        if (t < 160){ src=Wv2;  dst=W2T;            W=SDI; ldD=DM;  R0=(t%20)*64; C0=(t/20)*64; }
        else if (t < 320){ t-=160; src=Wpv2; dst=W2T + SDI*DM; W=SDI; ldD=DM; R0=(t%20)*64; C0=(t/20)*64; }
        else if (t < 360){ t-=320; src=Wek; dst=WekT; W=SDI; ldD=DD; R0=(t%20)*64; C0=(t/20)*64; }
        else if (t < 400){ t-=360; src=Wev; dst=WevT; W=SDI; ldD=DD; R0=(t%20)*64; C0=(t/20)*64; }
        else { t-=400; src=Wo; dst=WoT; W=DD; ldD=DI; R0=(t%2)*64; C0=(t/2)*64; }
        const int tx = tid & 63, ty = tid >> 6;
        #pragma unroll
        for (int k=0;k<16;++k){
            int c = C0 + 4*k + ty;
            sLT[tx*65 + 4*k + ty] = f2bf(src[(size_t)c*W + R0 + tx]);
        }
        __syncthreads();
        #pragma unroll
        for (int k=0;k<16;++k){
            int rr = 4*k + ty;
            dst[(size_t)(R0+rr)*ldD + C0 + tx] = sLT[rr*65 + tx];
        }
    } else if (bx < 664){
        const int node = bx - 408;
        if (tid < 64){
            float h0 = h[node*DD + tid], h1 = h[node*DD + 64 + tid];
            float s1 = h0 + h1, s2 = h0*h0 + h1*h1;
            #pragma unroll
            for (int off=32; off; off>>=1){ s1 += __shfl_xor(s1,off); s2 += __shfl_xor(s2,off); }
            float mu   = s1*(1.0f/DD);
            float var  = s2*(1.0f/DD) - mu*mu;
            float rstd = rsqrtf(var + 1e-5f);
            float c0 = (h0-mu)*rstd, c1 = (h1-mu)*rstd;
            hi_ws[node*DD + tid]      = f2bf(c0*g_hi[tid]);
            hi_ws[node*DD + 64 + tid] = f2bf(c1*g_hi[64+tid]);
            hj_ws[node*DD + tid]      = f2bf(c0*g_hj[tid]);
            hj_ws[node*DD + 64 + tid] = f2bf(c1*g_hj[64+tid]);
        }
        for (int f = node*256 + tid; f < 1584*DD; f += 256*256){
            int row = f >> 7, d = f & 127;
            float v;
            if (row < 256)       v = Wq[d*DI + row];
            else if (row < 304){ int c = row-256; v = (c < HS) ? Wg[d*HS + c] : 0.0f; }
            else if (row < 560)  v = Wk[d*DI + (row-304)];
            else if (row < 1072) v = Wv1[d*DM + (row-560)];
            else                 v = Wpv1[d*DM + (row-1072)];
            WnT[f] = f2bf(v);
        }
    } else {
        const int t = bx - 664;
        const int bb = t >> 7, j = t & 127;
        const int d = tid & 127, half = tid >> 7;
        if (half == 0){
            #pragma unroll
            for (int m=0;m<M1;++m)
                x1T[((size_t)(bb*M1+m)*NN + j)*DD + d] =
                    x1[(((size_t)bb*NN + j)*DD + d)*M1 + m];
        } else {
            #pragma unroll
            for (int m=0;m<M2;++m)
                x2T[((size_t)(bb*M2+m)*NN + j)*DD + d] =
                    x2[(((size_t)bb*NN + j)*DD + d)*M2 + m];
        }
    }
}

// ---------------------------------------------------------------------------
// node_gemm
// ---------------------------------------------------------------------------
__global__ __launch_bounds__(256,4) void node_gemm(
    const unsigned short* __restrict__ WnT,
    const unsigned short* __restrict__ hi_ws, const unsigned short* __restrict__ hj_ws,
    const float* __restrict__ bg, const float* __restrict__ bv1, const float* __restrict__ bpv1,
    float* __restrict__ q_ws, float* __restrict__ k_ws,
    float* __restrict__ g_ws, unsigned short* __restrict__ hid_ws)
{
    const int bx = blockIdx.x;
    const int tile = bx % 99, nq = bx / 99;
    const int tid = threadIdx.x, lane = tid&63, w = tid>>6;
    const int l15 = lane&15, g4 = lane>>4;
    const int ntile = nq*4 + w;
    const unsigned short* A  = WnT + (size_t)(tile*16 + l15)*DD + 8*g4;
    const unsigned short* Bp = ((tile < 19) ? hi_ws : hj_ws) + (size_t)(ntile*16 + l15)*DD + 8*g4;
    f32x4_t c = {0.f,0.f,0.f,0.f};
    #pragma unroll
    for (int ks=0; ks<4; ++ks)
        c = MFMA(*(const bf16x8_t*)(A + 32*ks), *(const bf16x8_t*)(Bp + 32*ks), c, 0,0,0);
    const int node = ntile*16 + l15;
    const int col0 = tile*16 + 4*g4;
    if (tile < 16){
        f32x4_t* dst = (f32x4_t*)(q_ws + (size_t)node*DI + col0);
        *dst = c;
    } else if (tile < 19){
        #pragma unroll
        for (int r=0;r<4;++r){
            int cc = col0 + r - 256;
            if (cc < HS) g_ws[node*HS + cc] = sigm(c[r] + bg[cc]);
        }
    } else if (tile < 35){
        f32x4_t* dst = (f32x4_t*)(k_ws + (size_t)node*DI + (col0-304));
        *dst = c;
    } else if (tile < 67){
        int cc = col0 - 560;
        float s0 = c[0]+bv1[cc], s1 = c[1]+bv1[cc+1], s2 = c[2]+bv1[cc+2], s3 = c[3]+bv1[cc+3];
        s0 *= sigm(s0); s1 *= sigm(s1); s2 *= sigm(s2); s3 *= sigm(s3);
        uint2 pkk; pkk.x = pk2(s0,s1); pkk.y = pk2(s2,s3);
        *(uint2*)(hid_ws + (size_t)node*1024 + cc) = pkk;
    } else {
        int cc = col0 - 1072;
        float s0 = c[0]+bpv1[cc], s1 = c[1]+bpv1[cc+1], s2 = c[2]+bpv1[cc+2], s3 = c[3]+bpv1[cc+3];
        s0 *= sigm(s0); s1 *= sigm(s1); s2 *= sigm(s2); s3 *= sigm(s3);
        uint2 pkk; pkk.x = pk2(s0,s1); pkk.y = pk2(s2,s3);
        *(uint2*)(hid_ws + (size_t)node*1024 + 512 + cc) = pkk;
    }
}

// ---------------------------------------------------------------------------
// v2_gemm
// ---------------------------------------------------------------------------
__global__ __launch_bounds__(256,4) void v2_gemm(
    const unsigned short* __restrict__ W2T,
    const unsigned short* __restrict__ hid_ws,
    const float* __restrict__ bv2, const float* __restrict__ bpv2,
    unsigned short* __restrict__ vpv_ws)
{
    const int bx = blockIdx.x;
    const int otile = bx % 160, nq = bx / 160;
    const int tid = threadIdx.x, lane = tid&63, w = tid>>6;
    const int l15 = lane&15, g4 = lane>>4;
    const int ntile = nq*4 + w;
    const int obase = otile*16;
    const int koff = (obase < SDI) ? 0 : 512;
    const unsigned short* A  = W2T + (size_t)(obase + l15)*DM + 8*g4;
    const unsigned short* Bp = hid_ws + (size_t)(ntile*16 + l15)*1024 + koff + 8*g4;
    f32x4_t c = {0.f,0.f,0.f,0.f};
    #pragma unroll
    for (int ks=0; ks<16; ++ks)
        c = MFMA(*(const bf16x8_t*)(A + 32*ks), *(const bf16x8_t*)(Bp + 32*ks), c, 0,0,0);
    const int node = ntile*16 + l15;
    const int o0 = obase + 4*g4;
    const float* bias = (obase < SDI) ? bv2 : bpv2;
    const int ob = (obase < SDI) ? o0 : (o0 - SDI);
    float v0 = c[0]+bias[ob], v1 = c[1]+bias[ob+1], v2 = c[2]+bias[ob+2], v3 = c[3]+bias[ob+3];
    uint2 pkk; pkk.x = pk2(v0,v1); pkk.y = pk2(v2,v3);
    *(uint2*)(vpv_ws + (size_t)node*2560 + o0) = pkk;
}

// ---------------------------------------------------------------------------
// simh (round-13 version): raw sim[j,h,s] per (node, j-half). LDS 60416.
// ---------------------------------------------------------------------------
#define SH_T   0
#define SH_QK  16384
#define SH_SIM 49152
#define SH_Q   59392

__global__ __launch_bounds__(512,4) void simh(
    const float* __restrict__ t_ij,
    const unsigned short* __restrict__ WekT,
    const float* __restrict__ q_ws, const float* __restrict__ k_ws,
    float* __restrict__ sim_ws)
{
    __shared__ __align__(16) char sm[60416];
    float* sSIM = (float*)(sm + SH_SIM);
    float* sQf  = (float*)(sm + SH_Q);

    const int bx0 = blockIdx.x;
    const int bx = ((bx0 & 7) << 6) | (bx0 >> 3);
    const int node = bx >> 1, jh = bx & 1;
    const int b = node >> 7;
    const int j0 = jh*64;
    const int tid = threadIdx.x, lane = tid&63, w = tid>>6;
    const int l15 = lane&15, g4 = lane>>4;

    if (tid < DI) sQf[tid] = q_ws[(size_t)node*DI + tid];
    {
        const int j = tid>>3, seg = tid&7;
        const float* src = t_ij + (size_t)(node*NN + j0 + j)*DD + seg*16;
        char* row = sm + SH_T + j*256;
        const int swz = (j&7)<<4;
        #pragma unroll
        for (int u=0;u<4;++u){
            f32x4v tv = __builtin_nontemporal_load((const f32x4v*)(src + 4*u));
            uint2 pkk; pkk.x = pk2(tv[0],tv[1]); pkk.y = pk2(tv[2],tv[3]);
            *(uint2*)(row + ((2*(seg*16+4*u)) ^ swz)) = pkk;
        }
    }
    __syncthreads();
    {
        const int j = tid>>3, seg = tid&7;
        const float* kr = k_ws + (size_t)(b*NN + j0 + j)*DI + seg*32;
        char* row = sm + SH_QK + j*512;
        const int swz = (j&7)<<4;
        #pragma unroll
        for (int u=0;u<8;++u){
            float4 kv = *(const float4*)(kr + 4*u);
            const float* qv = sQf + seg*32 + 4*u;
            uint2 pkk; pkk.x = pk2(kv.x*qv[0], kv.y*qv[1]); pkk.y = pk2(kv.z*qv[2], kv.w*qv[3]);
            *(uint2*)(row + ((2*(seg*32+4*u)) ^ swz)) = pkk;
        }
    }
    bf16x8_t bT[4][4];
    #pragma unroll
    for (int jt=0;jt<4;++jt){
        const int jc = jt*16 + l15;
        const char* row = sm + SH_T + jc*256;
        const int swz = (jc&7)<<4;
        #pragma unroll
        for (int ks=0;ks<4;++ks)
            bT[jt][ks] = *(const bf16x8_t*)(row + ((2*(32*ks+8*g4)) ^ swz));
    }
    __syncthreads();

    for (int p5=0; p5<5; ++p5){
        const int p = w + 8*p5;
        const unsigned short* ap = WekT + (size_t)(2*p)*16*DD + (size_t)l15*DD + 8*g4;
        bf16x8_t a0[4], a1[4];
        #pragma unroll
        for (int ks=0;ks<4;++ks){
            a0[ks] = *(const bf16x8_t*)(ap + 32*ks);
            a1[ks] = *(const bf16x8_t*)(ap + 16*DD + 32*ks);
        }
        const int hs = w*SS + p5;
        const int o0 = 32*p + 4*g4;
        const int qk0 = o0 & 255;
        #pragma unroll
        for (int jt=0;jt<4;++jt){
            f32x4_t c0 = {0.f,0.f,0.f,0.f}, c1 = {0.f,0.f,0.f,0.f};
            #pragma unroll
            for (int ks=0;ks<4;++ks){
                c0 = MFMA(a0[ks], bT[jt][ks], c0, 0,0,0);
                c1 = MFMA(a1[ks], bT[jt][ks], c1, 0,0,0);
            }
            const int jr = jt*16 + l15;
            const char* qrow = sm + SH_QK + jr*512;
            const int swz = (jr&7)<<4;
            uint2 u0 = *(const uint2*)(qrow + ((2*qk0) ^ swz));
            uint2 u1 = *(const uint2*)(qrow + ((2*(qk0+16)) ^ swz));
            float part =
                (c0[0]*sigm(c0[0]))*bflo(u0.x) + (c0[1]*sigm(c0[1]))*bfhi(u0.x)
              + (c0[2]*sigm(c0[2]))*bflo(u0.y) + (c0[3]*sigm(c0[3]))*bfhi(u0.y)
              + (c1[0]*sigm(c1[0]))*bflo(u1.x) + (c1[1]*sigm(c1[1]))*bfhi(u1.x)
              + (c1[2]*sigm(c1[2]))*bflo(u1.y) + (c1[3]*sigm(c1[3]))*bfhi(u1.y);
            part += __shfl_xor(part, 16);
            part += __shfl_xor(part, 32);
            if (g4 == 0) sSIM[jr*HS + hs] = part;
        }
    }
    __syncthreads();
    {
        float* dst = sim_ws + (size_t)node*NN*HS + j0*HS;
        for (int t2=tid; t2<64*HS; t2+=512) dst[t2] = sSIM[t2];
    }
}

// ---------------------------------------------------------------------------
// outh (round-13 structure, softmax FUSED): per (node, j-half).
//   staged softmax (full j-row reduce, gate-scaled, keep our half) -> sATT
//   s=0,1,2: EV GEMM -> f32 gsea -> register j-contraction -> p012
//   s=3,4  : EV GEMM -> sP -> @Wo -> x-weighted reductions -> p34
// ---------------------------------------------------------------------------
#define OH_T   0
#define OH_P   16384
#define OH_AT  49152
#define OH_G   59392
#define OH_W1  59552
#define OH_W2  60320

#define EV_BODY(S, EPILOG)                                                        \
    _Pragma("unroll")                                                             \
    for (int mloc=0; mloc<2; ++mloc){                                             \
        const int mt = w*2 + mloc;                                                \
        const int m0 = mt*16 + 4*g4;                                              \
        uint2 vvr[4], ppr[4];                                                     \
        _Pragma("unroll")                                                         \
        for (int jt=0;jt<4;++jt){                                                 \
            const unsigned short* vb = vpv_ws + (size_t)(b*NN + j0 + jt*16 + l15)*2560 + (S)*DI + m0; \
            vvr[jt] = *(const uint2*)vb;                                          \
            ppr[jt] = *(const uint2*)(vb + SDI);                                  \
        }                                                                         \
        const unsigned short* ap = WevT + (size_t)((S)*DI + mt*16 + l15)*DD + 8*g4; \
        bf16x8_t aa[4];                                                           \
        _Pragma("unroll")                                                         \
        for (int ks=0;ks<4;++ks) aa[ks] = *(const bf16x8_t*)(ap + 32*ks);         \
        const int hh = mt >> 1;                                                   \
        const float gtv = sG[hh*SS + (S)];                                        \
        _Pragma("unroll")                                                         \
        for (int jt=0;jt<4;++jt){                                                 \
            const int jc = jt*16 + l15;                                           \
            bf16x8_t bT[4];                                                       \
            {   const char* row_ = sm + OH_T + jc*256;                            \
                const int swz_ = (jc&7)<<4;                                       \
                _Pragma("unroll")                                                 \
                for (int ks=0;ks<4;++ks)                                          \
                    bT[ks] = *(const bf16x8_t*)(row_ + ((2*(32*ks+8*g4)) ^ swz_)); } \
            f32x4_t c = {0.f,0.f,0.f,0.f};                                        \
            _Pragma("unroll")                                                     \
            for (int ks=0;ks<4;++ks) c = MFMA(aa[ks], bT[ks], c, 0,0,0);          \
            const float atv = sATT[jc*HS + hh*SS + (S)];                          \
            float g_[4];                                                          \
            g_[0] = atv*bflo(vvr[jt].x) + gtv*c[0]*bflo(ppr[jt].x);               \
            g_[1] = atv*bfhi(vvr[jt].x) + gtv*c[1]*bfhi(ppr[jt].x);               \
            g_[2] = atv*bflo(vvr[jt].y) + gtv*c[2]*bflo(ppr[jt].y);               \
            g_[3] = atv*bfhi(vvr[jt].y) + gtv*c[3]*bfhi(ppr[jt].y);               \
            EPILOG                                                                \
        }                                                                         \
    }

#define WO_X(XT, MM, AX)                                                          \
    _Pragma("unroll")                                                             \
    for (int jt=0; jt<4; ++jt){                                                   \
        float xv[4*(MM)];                                                         \
        _Pragma("unroll")                                                         \
        for (int r_=0;r_<4;++r_){                                                 \
            const int jr = j0 + jt*16 + 4*g4 + r_;                                \
            _Pragma("unroll")                                                     \
            for (int m_=0;m_<(MM);++m_)                                           \
                xv[r_*(MM)+m_] = XT[((size_t)(b*(MM)+m_)*NN + jr)*DD + d];        \
        }                                                                         \
        const int arow = jt*16 + l15;                                             \
        const char* pbp = sm + OH_P + arow*512;                                   \
        const int aswz = (arow&7)<<4;                                             \
        f32x4_t c = {0.f,0.f,0.f,0.f};                                            \
        _Pragma("unroll")                                                         \
        for (int ks=0;ks<8;++ks){                                                 \
            bf16x8_t a = *(const bf16x8_t*)(pbp + ((64*ks + 16*g4) ^ aswz));      \
            c = MFMA(a, bWo[ks], c, 0,0,0);                                       \
        }                                                                         \
        _Pragma("unroll")                                                         \
        for (int r_=0;r_<4;++r_){                                                 \
            _Pragma("unroll")                                                     \
            for (int m_=0;m_<(MM);++m_) AX[m_] = fmaf(xv[r_*(MM)+m_], c[r_], AX[m_]); \
        }                                                                         \
    }

#define RED_WRITE(VAL, ROW, T_)                                                   \
    { float v_ = (VAL);                                                           \
      v_ += __shfl_xor(v_,1); v_ += __shfl_xor(v_,2);                             \
      v_ += __shfl_xor(v_,4); v_ += __shfl_xor(v_,8);                             \
      if (l15 == 0)                                                               \
          pdst[(ROW)*256 + (w*2 + ((T_)>>2))*16 + 4*g4 + ((T_)&3)] = v_; }

__global__ __launch_bounds__(512,4) void outh(
    const float* __restrict__ t_ij,
    const unsigned short* __restrict__ WevT, const unsigned short* __restrict__ WoT,
    const unsigned short* __restrict__ vpv_ws,
    const float* __restrict__ sim_ws,    // RAW sim (pre-softmax)
    const float* __restrict__ g_ws,
    const float* __restrict__ r1, const float* __restrict__ r2,
    const float* __restrict__ x1T, const float* __restrict__ x2T,
    float* __restrict__ p012, float* __restrict__ p34)
{
    __shared__ __align__(16) char sm[61600];
    float* sATT = (float*)(sm + OH_AT);
    float* sG   = (float*)(sm + OH_G);
    float* sW1  = (float*)(sm + OH_W1);
    float* sW2  = (float*)(sm + OH_W2);

    const int bx0 = blockIdx.x;
    const int bx = ((bx0 & 7) << 6) | (bx0 >> 3);   // XCD-contiguous remap
    const int node = bx >> 1, jh = bx & 1;
    const int b = node >> 7;
    const int j0 = jh*64;
    const int tid = threadIdx.x, lane = tid&63, w = tid>>6;
    const int l15 = lane&15, g4 = lane>>4;

    {   // stage T (64 rows) -> swizzled bf16
        const int j = tid>>3, seg = tid&7;
        const float* src = t_ij + (size_t)(node*NN + j0 + j)*DD + seg*16;
        char* row = sm + OH_T + j*256;
        const int swz = (j&7)<<4;
        #pragma unroll
        for (int u=0;u<4;++u){
            f32x4v tv = __builtin_nontemporal_load((const f32x4v*)(src + 4*u));
            uint2 pkk; pkk.x = pk2(tv[0],tv[1]); pkk.y = pk2(tv[2],tv[3]);
            *(uint2*)(row + ((2*(seg*16+4*u)) ^ swz)) = pkk;
        }
    }
    {   // FUSED softmax over full j, gate-scaled; keep our half in sATT.
        // wave w handles hs = w*5 .. w*5+4; lane (0..63) = local j of our half.
        const float* srow = sim_ws + (size_t)node*NN*HS;
        #pragma unroll
        for (int u=0; u<5; ++u){
            const int hs = w*5 + u;
            const float gt = g_ws[node*HS + hs];
            float v0 = srow[lane*HS + hs];
            float v1 = srow[(lane+64)*HS + hs];
            float m = fmaxf(v0,v1);
            #pragma unroll
            for (int off=32; off; off>>=1) m = fmaxf(m, __shfl_xor(m,off));
            float e0 = __expf(v0-m), e1 = __expf(v1-m);
            float ssum = e0+e1;
            #pragma unroll
            for (int off=32; off; off>>=1) ssum += __shfl_xor(ssum,off);
            const float inv = __fdividef(gt, ssum);
            sATT[lane*HS + hs] = ((jh==0) ? e0 : e1) * inv;
        }
    }
    if (tid < HS) sG[tid] = g_ws[node*HS + tid];
    if (tid < 64*M1) sW1[tid] = r1[((size_t)node*NN + j0)*M1 + tid];
    if (tid < 64*M2) sW2[tid] = r2[((size_t)node*NN + j0)*M2 + tid];
    __syncthreads();

    float* pdst = p012 + (size_t)(jh*256 + node)*9*256;

    // ---- s=0 ----
    {
        float a0[8] = {0,0,0,0,0,0,0,0};
        EV_BODY(0, {
            _Pragma("unroll")
            for (int k_=0;k_<4;++k_) a0[mloc*4+k_] += g_[k_];
        })
        #pragma unroll
        for (int t_=0;t_<8;++t_) RED_WRITE(a0[t_], 0, t_)
    }
    // ---- s=1 ----
    {
        float a1[M1][8];
        #pragma unroll
        for (int m_=0;m_<M1;++m_)
            #pragma unroll
            for (int t_=0;t_<8;++t_) a1[m_][t_] = 0.f;
        EV_BODY(1, {
            _Pragma("unroll")
            for (int m_=0;m_<M1;++m_){
                const float wgt = sW1[jc*M1 + m_];
                _Pragma("unroll")
                for (int k_=0;k_<4;++k_) a1[m_][mloc*4+k_] = fmaf(wgt, g_[k_], a1[m_][mloc*4+k_]);
            }
        })
        #pragma unroll
        for (int m_=0;m_<M1;++m_)
            #pragma unroll
            for (int t_=0;t_<8;++t_) RED_WRITE(a1[m_][t_], 1+m_, t_)
    }
    // ---- s=2 ----
    {
        float a2[M2][8];
        #pragma unroll
        for (int m_=0;m_<M2;++m_)
            #pragma unroll
            for (int t_=0;t_<8;++t_) a2[m_][t_] = 0.f;
        EV_BODY(2, {
            _Pragma("unroll")
            for (int m_=0;m_<M2;++m_){
                const float wgt = sW2[jc*M2 + m_];
                _Pragma("unroll")
                for (int k_=0;k_<4;++k_) a2[m_][mloc*4+k_] = fmaf(wgt, g_[k_], a2[m_][mloc*4+k_]);
            }
        })
        #pragma unroll
        for (int m_=0;m_<M2;++m_)
            #pragma unroll
            for (int t_=0;t_<8;++t_) RED_WRITE(a2[m_][t_], 4+m_, t_)
    }

    // ---- s=3,4 ----
    const int d = w*16 + l15;
    bf16x8_t bWo[8];
    {
        const unsigned short* wr = WoT + (size_t)d*DI + 8*g4;
        #pragma unroll
        for (int ks=0;ks<8;++ks) bWo[ks] = *(const bf16x8_t*)(wr + 32*ks);
    }
    float ax1[M1] = {0.f,0.f,0.f};
    float ax2[M2] = {0.f,0.f,0.f,0.f,0.f};

    EV_BODY(3, {
        uint2 pkk; pkk.x = pk2(g_[0],g_[1]); pkk.y = pk2(g_[2],g_[3]);
        *(uint2*)(sm + OH_P + jc*512 + ((2*m0) ^ ((jc&7)<<4))) = pkk;
    })
    __syncthreads();
    WO_X(x1T, M1, ax1)
    __syncthreads();
    EV_BODY(4, {
        uint2 pkk; pkk.x = pk2(g_[0],g_[1]); pkk.y = pk2(g_[2],g_[3]);
        *(uint2*)(sm + OH_P + jc*512 + ((2*m0) ^ ((jc&7)<<4))) = pkk;
    })
    __syncthreads();
    WO_X(x2T, M2, ax2)

    // reduce ax over g4, write p34
    {
        float v0 = ax1[0], v1 = ax1[1], v2 = ax1[2];
        float v3 = ax2[0], v4 = ax2[1], v5 = ax2[2], v6 = ax2[3], v7 = ax2[4];
        v0 += __shfl_xor(v0,16); v0 += __shfl_xor(v0,32);
        v1 += __shfl_xor(v1,16); v1 += __shfl_xor(v1,32);
        v2 += __shfl_xor(v2,16); v2 += __shfl_xor(v2,32);
        v3 += __shfl_xor(v3,16); v3 += __shfl_xor(v3,32);
        v4 += __shfl_xor(v4,16); v4 += __shfl_xor(v4,32);
        v5 += __shfl_xor(v5,16); v5 += __shfl_xor(v5,32);
        v6 += __shfl_xor(v6,16); v6 += __shfl_xor(v6,32);
        v7 += __shfl_xor(v7,16); v7 += __shfl_xor(v7,32);
        if (g4 == 0){
            float* pb = p34 + (size_t)bx*8*DD + d;
            pb[0*DD] = v0; pb[1*DD] = v1; pb[2*DD] = v2;
            pb[3*DD] = v3; pb[4*DD] = v4; pb[5*DD] = v5;
            pb[6*DD] = v6; pb[7*DD] = v7;
        }
    }
}

// ---------------------------------------------------------------------------
// combine: z = sum(p012 halves); out = z @ Wo + p34 sums + residual.
// ---------------------------------------------------------------------------
__global__ __launch_bounds__(128) void combine(
    const float* __restrict__ h, const unsigned short* __restrict__ WoT,
    const float* __restrict__ p012, const float* __restrict__ p34,
    float* __restrict__ out_h, float* __restrict__ out_x1, float* __restrict__ out_x2)
{
    __shared__ float sZ[256*12];
    const int node = blockIdx.x, d = threadIdx.x;
    const float* pa = p012 + ((size_t)node*9)*256;
    const float* pb = p012 + ((size_t)(256 + node)*9)*256;
    for (int t=d; t<2304; t+=128){
        int m = t >> 8, c = t & 255;
        sZ[c*12 + m] = pa[t] + pb[t];
    }
    __syncthreads();
    float az[9] = {0.f,0.f,0.f,0.f,0.f,0.f,0.f,0.f,0.f};
    const unsigned short* wr = WoT + (size_t)d*DI;
    for (int cb=0; cb<32; ++cb){
        uint4 wv = *(const uint4*)(wr + cb*8);
        float wk[8];
        wk[0]=bflo(wv.x); wk[1]=bfhi(wv.x); wk[2]=bflo(wv.y); wk[3]=bfhi(wv.y);
        wk[4]=bflo(wv.z); wk[5]=bfhi(wv.z); wk[6]=bflo(wv.w); wk[7]=bfhi(wv.w);
        #pragma unroll
        for (int k=0;k<8;++k){
            const float* zb = sZ + (cb*8+k)*12;
            float4 za = *(const float4*)zb;
            float4 zbv = *(const float4*)(zb+4);
            float z8 = zb[8];
            az[0] = fmaf(za.x,  wk[k], az[0]);
            az[1] = fmaf(za.y,  wk[k], az[1]);
            az[2] = fmaf(za.z,  wk[k], az[2]);
            az[3] = fmaf(za.w,  wk[k], az[3]);
            az[4] = fmaf(zbv.x, wk[k], az[4]);
            az[5] = fmaf(zbv.y, wk[k], az[5]);
            az[6] = fmaf(zbv.z, wk[k], az[6]);
            az[7] = fmaf(zbv.w, wk[k], az[7]);
            az[8] = fmaf(z8,    wk[k], az[8]);
        }
    }
    float p34v[8];
    #pragma unroll
    for (int row=0; row<8; ++row){
        p34v[row] = p34[((size_t)(node*2+0)*8 + row)*DD + d]
                  + p34[((size_t)(node*2+1)*8 + row)*DD + d];
    }
    out_h[(size_t)node*DD + d] = h[(size_t)node*DD + d] + az[0];
    #pragma unroll
    for (int m=0;m<M1;++m)
        out_x1[((size_t)node*DD + d)*M1 + m] = az[1+m] + p34v[m];
    #pragma unroll
    for (int m=0;m<M2;++m)
        out_x2[((size_t)node*DD + d)*M2 + m] = az[4+m] + p34v[3+m];
}

// ---------------------------------------------------------------------------
extern "C" void kernel_launch(void* const* d_in, const int* in_sizes, int n_in,
                              void* d_out, int out_size, void* d_ws, size_t ws_size,
                              hipStream_t stream)
{
    (void)in_sizes; (void)n_in; (void)out_size; (void)ws_size;
    const float* h    = (const float*)d_in[0];
    const float* t_ij = (const float*)d_in[1];
    const float* r1   = (const float*)d_in[2];
    const float* r2   = (const float*)d_in[3];
    const float* x1   = (const float*)d_in[4];
    const float* x2   = (const float*)d_in[5];
    const float* g_hi = (const float*)d_in[6];
    const float* g_hj = (const float*)d_in[7];
    const float* Wq   = (const float*)d_in[8];
    const float* Wk   = (const float*)d_in[9];
    const float* Wv1  = (const float*)d_in[10];
    const float* bv1  = (const float*)d_in[11];
    const float* Wv2  = (const float*)d_in[12];
    const float* bv2  = (const float*)d_in[13];
    const float* Wpv1 = (const float*)d_in[14];
    const float* bpv1 = (const float*)d_in[15];
    const float* Wpv2 = (const float*)d_in[16];
    const float* bpv2 = (const float*)d_in[17];
    const float* Wek  = (const float*)d_in[18];
    const float* Wev  = (const float*)d_in[19];
    const float* Wg   = (const float*)d_in[20];
    const float* bg   = (const float*)d_in[21];
    const float* Wo   = (const float*)d_in[22];

    float* fb     = (float*)d_ws;
    float* q_ws   = fb;                       // 65536
    float* k_ws   = q_ws   + 65536;           // 65536
    float* g_ws   = k_ws   + 65536;           // 10240
    float* sim_ws = g_ws   + 10240;           // 1310720
    float* p012   = sim_ws + 1310720;         // 1179648
    float* p34    = p012   + 1179648;         // 524288
    float* x1T    = p34    + 524288;          // 98304
    float* x2T    = x1T    + 98304;           // 163840
    unsigned short* hi_ws  = (unsigned short*)(x2T + 163840);
    unsigned short* hj_ws  = hi_ws  + 32768;
    unsigned short* hid_ws = hj_ws  + 32768;  // 262144
    unsigned short* vpv_ws = hid_ws + 262144; // 655360
    unsigned short* WekT   = vpv_ws + 655360; // 163840
    unsigned short* WevT   = WekT   + 163840; // 163840
    unsigned short* WoT    = WevT   + 163840; // 32768
    unsigned short* W2T    = WoT    + 32768;  // 1310720
    unsigned short* WnT    = W2T    + 1310720;// 202752

    float* out_h  = (float*)d_out;
    float* out_x1 = out_h  + BB*NN*DD;
    float* out_x2 = out_x1 + BB*NN*DD*M1;

    prep<<<920, 256, 0, stream>>>(h, g_hi, g_hj, Wq, Wk, Wv1, Wpv1, Wg,
        Wek, Wev, Wo, Wv2, Wpv2, x1, x2,
        hi_ws, hj_ws, WekT, WevT, WoT, W2T, WnT, x1T, x2T);

    node_gemm<<<396, 256, 0, stream>>>(WnT, hi_ws, hj_ws, bg, bv1, bpv1,
        q_ws, k_ws, g_ws, hid_ws);

    v2_gemm<<<640, 256, 0, stream>>>(W2T, hid_ws, bv2, bpv2, vpv_ws);

    simh<<<512, 512, 0, stream>>>(t_ij, WekT, q_ws, k_ws, sim_ws);

    outh<<<512, 512, 0, stream>>>(t_ij, WevT, WoT, vpv_ws, sim_ws, g_ws,
        r1, r2, x1T, x2T, p012, p34);

    combine<<<256, 128, 0, stream>>>(h, WoT, p012, p34, out_h, out_x1, out_x2);
}